// Round 6
// baseline (444.534 us; speedup 1.0000x reference)
//
#include <hip/hip_runtime.h>
#include <hip/hip_cooperative_groups.h>
#include <stdint.h>

// BotBlock pipeline, MFMA version (round 6).
// Block space: 8192 independent 4x4x64 blocks (raw-reshape semantics).
// buf (ws) bf16 NHWC block space: buf[row*64 + c], row = b*16 + p.
// Convs = im2col GEMMs, K = 576 (9 taps x 64 ch), bf16 MFMA 16x16x32, fp32 acc.
// conv3+stats3+BN3+relu fused into ONE cooperative kernel (2 grid syncs);
// falls back to split kernels if cooperative launch is rejected.
// attn: qkv+rel-logits via one MFMA GEMM (16 tiles), f32 LDS attention core.

#define EPSV 1e-5f
#define INV_N (1.0f / 131072.0f)

typedef unsigned short u16;
typedef __attribute__((ext_vector_type(8))) short short8b;  // 8 bf16
typedef __attribute__((ext_vector_type(4))) float f32x4;

__device__ __forceinline__ u16 f2bf(float f) {
  unsigned u = __float_as_uint(f);
  u += 0x7fffu + ((u >> 16) & 1u);
  return (u16)(u >> 16);
}
__device__ __forceinline__ float bf2f(u16 h) {
  return __uint_as_float((unsigned)h << 16);
}
__device__ __forceinline__ unsigned cvtpk(float lo, float hi) {
  unsigned r;
  asm("v_cvt_pk_bf16_f32 %0, %1, %2" : "=v"(r) : "v"(lo), "v"(hi));
  return r;
}

__device__ __forceinline__ float bn_scale(const float* __restrict__ acc,
                                          const float* __restrict__ gam,
                                          const float* __restrict__ bet,
                                          int C, int c, float& shift) {
  float S = acc[c], S2 = acc[C + c];
  float mean = S * INV_N;
  float var  = S2 * INV_N - mean * mean;
  float rstd = rsqrtf(var + EPSV);
  float sc = gam[c] * rstd;
  shift = bet[c] - mean * sc;
  return sc;
}

// ---------- prep: conv1 w -> [18][64][40]; conv3 w -> [9][256][64]; qkv+rel -> [256][64] ----------
__global__ __launch_bounds__(256) void prep_kernel(const float* __restrict__ w1,
                                                   const float* __restrict__ w3,
                                                   const float* __restrict__ wq,
                                                   const float* __restrict__ wk,
                                                   const float* __restrict__ wv,
                                                   const float* __restrict__ relw,
                                                   const float* __restrict__ relh,
                                                   u16* __restrict__ wp1,
                                                   u16* __restrict__ wp3,
                                                   u16* __restrict__ wqkvT) {
  int i = blockIdx.x * 256 + threadIdx.x;
  const int tot1 = 18 * 64 * 40;       // 46080
  const int tot3 = 9 * 256 * 64;       // 147456
  if (i < tot1) {
    int ch = i / (64 * 40); int r = i - ch * 64 * 40; int o = r / 40; int kk = r - o * 40;
    float v = 0.f;
    if (kk < 32) { int k = ch * 32 + kk; int tap = k >> 6; int c = k & 63;
                   v = w1[o * 576 + c * 9 + tap]; }
    wp1[i] = f2bf(v);
  } else if (i < tot1 + tot3) {
    int j = i - tot1;
    int tap = j >> 14; int r = j & 16383; int o = r >> 6; int c = r & 63;
    wp3[j] = f2bf(w3[o * 576 + c * 9 + tap]);
  } else if (i < tot1 + tot3 + 192 * 64) {
    int j = i - tot1 - tot3;
    int oc = j >> 6, c = j & 63;
    const float* src = (oc < 64) ? wq : (oc < 128) ? wk : wv;
    wqkvT[j] = f2bf(src[(c << 6) + (oc & 63)]);
  } else if (i < tot1 + tot3 + 192 * 64 + 4096) {
    int j = i - tot1 - tot3 - 192 * 64;  // 0..4095
    int c = j & 63; int col = (j >> 6) & 31; int tbl = j >> 11;
    int n = col >> 3, m = col & 7;
    float v = 0.f;
    if (m < 7) {
      const float* rel = tbl ? relh : relw;
#pragma unroll
      for (int d = 0; d < 16; ++d) v += wq[c * 64 + n * 16 + d] * rel[m * 16 + d];
    }
    wqkvT[(192 + tbl * 32 + col) * 64 + c] = f2bf(v);
  }
}

// ---------- conv1: x (NCHW blocks, fp32) -> buf (NHWC bf16) + fused stats1 ----------
__global__ __launch_bounds__(256) void conv1_kernel(const float* __restrict__ x,
                                                    const u16* __restrict__ wp,
                                                    u16* __restrict__ bufb,
                                                    float* __restrict__ partials1) {
  __shared__ __align__(16) char featA[257 * 128];   // bf16 [row][64ch], swizzled; row 256 = zeros
  __shared__ __align__(16) char ldsW[2][64 * 80];   // [o][40 bf16] per 32-k chunk
  const int t = threadIdx.x;
  const int lane = t & 63, w = t >> 6;
  const int lrow = lane & 15, lk = lane >> 4;
  const int wm = w >> 1, wn = w & 1;                // wave tile: 128 rows x 32 o
  const size_t Mbase = (size_t)blockIdx.x * 256;

  int rel[9];
  {
    const int pi = lrow >> 2, pj = lrow & 3;
#pragma unroll
    for (int tap = 0; tap < 9; ++tap) {
      const int ti = tap / 3, tj = tap - ti * 3;
      int si = pi + ti - 1, sj = pj + tj - 1;
      bool valid = ((unsigned)si < 4u) && ((unsigned)sj < 4u);
      rel[tap] = valid ? ((si * 4 + sj) << 7) : (1 << 24);
    }
  }

  // staging: thread -> c-pair cp (0..31), p-half ph (0..7); pair-packed b32 LDS writes
  {
    const int cp = t >> 3, ph = t & 7;
    const int gsw = ((cp >> 2) << 4) | ((cp & 3) << 2);   // granule-col part of swizzle
#pragma unroll
    for (int i = 0; i < 16; ++i) {
      const float* bp = x + Mbase * 64 + i * 1024 + cp * 32 + ph * 2;
      float2 a = *reinterpret_cast<const float2*>(bp);
      float2 b = *reinterpret_cast<const float2*>(bp + 16);
#pragma unroll
      for (int j = 0; j < 2; ++j) {
        const int row = i * 16 + ph * 2 + j;
        unsigned pk = cvtpk(j ? a.y : a.x, j ? b.y : b.x);
        const int byte = row * 128 + (gsw ^ ((row & 7) << 4));
        *reinterpret_cast<unsigned*>(featA + byte) = pk;
      }
    }
  }
  if (t < 8) *reinterpret_cast<uint4*>(featA + 256 * 128 + t * 16) = uint4{0, 0, 0, 0};

  uint4 s0, s1;
  {
    const u16* sp = wp;
    s0 = *reinterpret_cast<const uint4*>(sp + (size_t)t * 8);
    if (t < 64) s1 = *reinterpret_cast<const uint4*>(sp + (size_t)(t + 256) * 8);
    *reinterpret_cast<uint4*>(ldsW[0] + t * 16) = s0;
    if (t < 64) *reinterpret_cast<uint4*>(ldsW[0] + (t + 256) * 16) = s1;
  }
  __syncthreads();

  f32x4 acc[8][2] = {};
#pragma unroll
  for (int chn = 0; chn < 18; ++chn) {
    const int cur = chn & 1;
    const int tap = chn >> 1, kk = chn & 1;
    if (chn + 1 < 18) {
      const u16* sp = wp + (chn + 1) * 2560;
      s0 = *reinterpret_cast<const uint4*>(sp + (size_t)t * 8);
      if (t < 64) s1 = *reinterpret_cast<const uint4*>(sp + (size_t)(t + 256) * 8);
    }
    const int kkg = (kk << 6) | (lk << 4);
    short8b bw[2];
#pragma unroll
    for (int n = 0; n < 2; ++n)
      bw[n] = *reinterpret_cast<const short8b*>(ldsW[cur] + (wn * 32 + n * 16 + lrow) * 80 + lk * 16);
#pragma unroll
    for (int m = 0; m < 8; ++m) {
      int ad = ((wm * 128 + m * 16) << 7) + rel[tap];
      ad = ad < 32768 ? ad : 32768;
      ad += (kkg ^ ((ad >> 3) & 0x70));
      short8b af = *reinterpret_cast<const short8b*>(featA + ad);
#pragma unroll
      for (int n = 0; n < 2; ++n)
        acc[m][n] = __builtin_amdgcn_mfma_f32_16x16x32_bf16(af, bw[n], acc[m][n], 0, 0, 0);
    }
    if (chn + 1 < 18) {
      *reinterpret_cast<uint4*>(ldsW[cur ^ 1] + t * 16) = s0;
      if (t < 64) *reinterpret_cast<uint4*>(ldsW[cur ^ 1] + (t + 256) * 16) = s1;
    }
    __syncthreads();
  }

  // bf16 NHWC stores
#pragma unroll
  for (int m = 0; m < 8; ++m) {
    const size_t rowg0 = Mbase + wm * 128 + m * 16 + lk * 4;
#pragma unroll
    for (int n = 0; n < 2; ++n) {
      const int o = wn * 32 + n * 16 + lrow;
#pragma unroll
      for (int r = 0; r < 4; ++r)
        bufb[(rowg0 + r) * 64 + o] = f2bf(acc[m][n][r]);
    }
  }

  // fused stats1 (channel = o)
  float* pst = reinterpret_cast<float*>(featA);    // [S 64][S2 64]
  if (t < 128) pst[t] = 0.f;
  __syncthreads();
#pragma unroll
  for (int n = 0; n < 2; ++n) {
    float s = 0.f, s2 = 0.f;
#pragma unroll
    for (int m = 0; m < 8; ++m)
#pragma unroll
      for (int r = 0; r < 4; ++r) {
        float v = acc[m][n][r];
        s += v; s2 = fmaf(v, v, s2);
      }
    s += __shfl_xor(s, 16); s2 += __shfl_xor(s2, 16);
    s += __shfl_xor(s, 32); s2 += __shfl_xor(s2, 32);
    if (lk == 0) {
      const int o = wn * 32 + n * 16 + lrow;
      atomicAdd(&pst[o], s);
      atomicAdd(&pst[64 + o], s2);
    }
  }
  __syncthreads();
  if (t < 128) partials1[(size_t)blockIdx.x * 128 + t] = pst[t];
}

// ---------- generic partial reduce for stats1/stats2 (stride 128) ----------
__global__ __launch_bounds__(256) void reduce12_kernel(const float* __restrict__ p,
                                                       float* __restrict__ acc, int nrows) {
  const int c = blockIdx.x, t = threadIdx.x;
  float s = 0.f;
  for (int i = t; i < nrows; i += 256) s += p[(size_t)i * 128 + c];
#pragma unroll
  for (int off = 32; off > 0; off >>= 1) s += __shfl_down(s, off);
  __shared__ float red[4];
  if ((t & 63) == 0) red[t >> 6] = s;
  __syncthreads();
  if (t == 0) acc[c] = red[0] + red[1] + red[2] + red[3];
}

// ---------- attn: BN1+relu -> qkv+rel (MFMA) -> attn core (f32 LDS) -> buf bf16 + stats2 ----------
// Per-wave f32 LDS Wf (3200 floats): Q base 0 (head 272, row 17);
// K base 1088, V base 2144 (head 264, row 16, col-group XOR).
// relLs per wave (1152 floats): [tbl 2][n 4][pos 16][9].
__global__ __launch_bounds__(256) void attn_kernel(u16* __restrict__ buf,
                                                   const u16* __restrict__ wqkvT,
                                                   const float* __restrict__ acc1,
                                                   const float* __restrict__ g1,
                                                   const float* __restrict__ b1,
                                                   float* __restrict__ partials2) {
  __shared__ float scsh[64][2];
  __shared__ float pstA[128];
  __shared__ __align__(16) u16 feat_l[4][1024];
  __shared__ __align__(16) float qkvf[4][3200];
  __shared__ __align__(16) float relLs[4][1152];
  const int t = threadIdx.x, u = t >> 6, lane = t & 63;
  const size_t b = (size_t)blockIdx.x * 4 + u;
  float* Wf = qkvf[u];
  float* rL = relLs[u];

  if (t < 64) {
    float sh; float sc = bn_scale(acc1, g1, b1, 64, t, sh);
    scsh[t][0] = sc; scsh[t][1] = sh;
  }
  if (t < 128) pstA[t] = 0.f;
  __syncthreads();

  // ---- stage feat (BN1+relu on bf16 buf) ----
  {
    const int pos = lane >> 2, cq = lane & 3;
    const u16* src = buf + b * 1024 + pos * 64 + cq * 16;
    short8b v0 = *reinterpret_cast<const short8b*>(src);
    short8b v1 = *reinterpret_cast<const short8b*>(src + 8);
    float f[16];
#pragma unroll
    for (int j = 0; j < 8; ++j) {
      const int c0 = cq * 16 + j, c1 = cq * 16 + 8 + j;
      f[j]     = fmaxf(fmaf(bf2f((u16)v0[j]), scsh[c0][0], scsh[c0][1]), 0.f);
      f[8 + j] = fmaxf(fmaf(bf2f((u16)v1[j]), scsh[c1][0], scsh[c1][1]), 0.f);
    }
    uint4 q0{cvtpk(f[0], f[1]), cvtpk(f[2], f[3]), cvtpk(f[4], f[5]), cvtpk(f[6], f[7])};
    uint4 q1{cvtpk(f[8], f[9]), cvtpk(f[10], f[11]), cvtpk(f[12], f[13]), cvtpk(f[14], f[15])};
    const int g0 = (cq * 2) ^ (pos & 7), g1g = (cq * 2 + 1) ^ (pos & 7);
    *reinterpret_cast<uint4*>(&feat_l[u][pos * 64 + g0 * 8]) = q0;
    *reinterpret_cast<uint4*>(&feat_l[u][pos * 64 + g1g * 8]) = q1;
  }

  // ---- qkv + rel via MFMA (16 col tiles) ----
  const int dq = lane & 15, lk = lane >> 4;
  short8b afr[2];
#pragma unroll
  for (int ch = 0; ch < 2; ++ch) {
    const int kg = ch * 4 + lk;
    afr[ch] = *reinterpret_cast<const short8b*>(&feat_l[u][dq * 64 + ((kg ^ (dq & 7)) * 8)]);
  }
#pragma unroll
  for (int ct = 0; ct < 16; ++ct) {
    f32x4 d = {0.f, 0.f, 0.f, 0.f};
#pragma unroll
    for (int ch = 0; ch < 2; ++ch) {
      short8b bfr = *reinterpret_cast<const short8b*>(&wqkvT[(ct * 16 + dq) * 64 + ch * 32 + lk * 8]);
      d = __builtin_amdgcn_mfma_f32_16x16x32_bf16(afr[ch], bfr, d, 0, 0, 0);
    }
    if (ct < 4) {
      float* dst = Wf + ct * 272;
#pragma unroll
      for (int r = 0; r < 4; ++r) dst[(lk * 4 + r) * 17 + dq] = d[r] * 0.25f;
    } else if (ct < 12) {
      float* dst = (ct < 8) ? (Wf + 1088 + (ct - 4) * 264) : (Wf + 2144 + (ct - 8) * 264);
      const int cp = dq ^ (lk << 2);
#pragma unroll
      for (int r = 0; r < 4; ++r) dst[(lk * 4 + r) * 16 + cp] = d[r];
    } else {
      const int rc = ct - 12, tbl = rc >> 1;
      const int nn = ((rc & 1) << 1) | (dq >> 3), mm = dq & 7;
      float* dst = rL + tbl * 576 + nn * 144 + mm;
#pragma unroll
      for (int r = 0; r < 4; ++r) dst[(lk * 4 + r) * 9] = d[r] * 0.25f;
    }
  }

  // ---- attention core: thread = (head n=lk, query pos qp=dq) ----
  const int n = lk, qp = dq;
  const int qi = qp >> 2, qj = qp & 3;
  float q_[16];
  {
    const float* qb = Wf + n * 272 + qp * 17;
#pragma unroll
    for (int d2 = 0; d2 < 16; ++d2) q_[d2] = qb[d2];
  }
  float rwq[4], rhq[4];
  {
    const float* rw = rL + n * 144 + qp * 9 + (3 - qj);
    const float* rh = rL + 576 + n * 144 + qp * 9 + (3 - qi);
#pragma unroll
    for (int k = 0; k < 4; ++k) { rwq[k] = rw[k]; rhq[k] = rh[k]; }
  }
  float lo[16]; float mx = -1e30f;
  const float* kbase = Wf + 1088 + n * 264;
#pragma unroll
  for (int kp = 0; kp < 16; ++kp) {
    const float4* kr = reinterpret_cast<const float4*>(kbase + kp * 16);
    float s = rwq[kp & 3] + rhq[kp >> 2];
#pragma unroll
    for (int g = 0; g < 4; ++g) {
      float4 kv = kr[g];
      const int lg = (g ^ (kp >> 2)) * 4;
      s = fmaf(q_[lg], kv.x, s); s = fmaf(q_[lg + 1], kv.y, s);
      s = fmaf(q_[lg + 2], kv.z, s); s = fmaf(q_[lg + 3], kv.w, s);
    }
    lo[kp] = s; mx = fmaxf(mx, s);
  }
  float ssum = 0.f;
#pragma unroll
  for (int kp = 0; kp < 16; ++kp) { float e = __expf(lo[kp] - mx); lo[kp] = e; ssum += e; }
  const float inv = 1.0f / ssum;
  float ov[16];
#pragma unroll
  for (int j = 0; j < 16; ++j) ov[j] = 0.f;
  const float* vbase = Wf + 2144 + n * 264;
#pragma unroll
  for (int kp = 0; kp < 16; ++kp) {
    const float4* vr = reinterpret_cast<const float4*>(vbase + kp * 16);
    const float wgt = lo[kp];
#pragma unroll
    for (int g = 0; g < 4; ++g) {
      float4 vv = vr[g];
      const int lg = (g ^ (kp >> 2)) * 4;
      ov[lg] = fmaf(wgt, vv.x, ov[lg]);
      ov[lg + 1] = fmaf(wgt, vv.y, ov[lg + 1]);
      ov[lg + 2] = fmaf(wgt, vv.z, ov[lg + 2]);
      ov[lg + 3] = fmaf(wgt, vv.w, ov[lg + 3]);
    }
  }
#pragma unroll
  for (int j = 0; j < 16; ++j) ov[j] *= inv;

  // bf16 output write (cvt_pk packed)
  {
    uint4 o0{cvtpk(ov[0], ov[1]), cvtpk(ov[2], ov[3]), cvtpk(ov[4], ov[5]), cvtpk(ov[6], ov[7])};
    uint4 o1{cvtpk(ov[8], ov[9]), cvtpk(ov[10], ov[11]), cvtpk(ov[12], ov[13]), cvtpk(ov[14], ov[15])};
    u16* dstb = buf + b * 1024 + qp * 64 + (n << 4);
    *reinterpret_cast<uint4*>(dstb) = o0;
    *reinterpret_cast<uint4*>(dstb + 8) = o1;
  }

  // ---- fused stats2: per-wave LDS transpose (reuse Wf), column sums ----
  {
    float* fl = Wf;                                       // [16 pos][69]
#pragma unroll
    for (int j = 0; j < 16; ++j) fl[qp * 69 + n * 16 + j] = ov[j];
    const int c = lane;
    float s = 0.f, s2 = 0.f;
#pragma unroll
    for (int pos = 0; pos < 16; ++pos) {
      float v = fl[pos * 69 + c];
      s += v; s2 = fmaf(v, v, s2);
    }
    atomicAdd(&pstA[c], s);
    atomicAdd(&pstA[64 + c], s2);
  }
  __syncthreads();
  if (t < 128) partials2[(size_t)blockIdx.x * 128 + t] = pstA[t];
}

// ======================================================================
// conv3 cooperative: BN2+relu -> conv3 (both o-halves) -> stats3 -> BN3+relu -> d_out
// grid MUST be 512 x 256thr, 2 blocks/CU co-resident.
// ======================================================================
__global__ __launch_bounds__(256, 2) void conv3_coop(const u16* __restrict__ src,
                                                     const u16* __restrict__ wp,
                                                     const float* __restrict__ acc2,
                                                     const float* __restrict__ g2,
                                                     const float* __restrict__ b2,
                                                     const float* __restrict__ g3,
                                                     const float* __restrict__ b3,
                                                     float* __restrict__ out,
                                                     u16* __restrict__ y3a,
                                                     float* __restrict__ p3,
                                                     float* __restrict__ acc3) {
  __shared__ __align__(16) u16 featB[257 * 64];
  __shared__ __align__(16) u16 ldsW[2][128 * 64];
  __shared__ float scsh[128];
  __shared__ float pst[256];
  const int t = threadIdx.x, wg = blockIdx.x;
  const int lane = t & 63, w = t >> 6;
  const int lrow = lane & 15, lk = lane >> 4;
  const int wm = w >> 1, wn = w & 1;
  const int Nbase = wg * 256;

  int rel[9];
  {
    const int pi = lrow >> 2, pj = lrow & 3;
#pragma unroll
    for (int tap = 0; tap < 9; ++tap) {
      const int ti = tap / 3, tj = tap - ti * 3;
      int si = pi + ti - 1, sj = pj + tj - 1;
      bool valid = ((unsigned)si < 4u) && ((unsigned)sj < 4u);
      rel[tap] = valid ? ((si * 4 + sj) << 7) : (1 << 24);
    }
  }

  if (t < 64) {
    float sh; float sc = bn_scale(acc2, g2, b2, 64, t, sh);
    scsh[t * 2] = sc; scsh[t * 2 + 1] = sh;
  }

  const int so = t >> 1, shalf = t & 1, so7 = so & 7;
  // W tap0 (half 0)
  {
    const u16* wsrc = wp + so * 64 + shalf * 32;
    uint4 w0 = *reinterpret_cast<const uint4*>(wsrc);
    uint4 w1 = *reinterpret_cast<const uint4*>(wsrc + 8);
    uint4 w2 = *reinterpret_cast<const uint4*>(wsrc + 16);
    uint4 w3v = *reinterpret_cast<const uint4*>(wsrc + 24);
    char* dst = (char*)ldsW[0] + so * 128;
    const int gb = shalf * 4;
    *reinterpret_cast<uint4*>(dst + (((gb + 0) ^ so7) << 4)) = w0;
    *reinterpret_cast<uint4*>(dst + (((gb + 1) ^ so7) << 4)) = w1;
    *reinterpret_cast<uint4*>(dst + (((gb + 2) ^ so7) << 4)) = w2;
    *reinterpret_cast<uint4*>(dst + (((gb + 3) ^ so7) << 4)) = w3v;
  }
  __syncthreads();

  // featB staging (BN2+relu), staged ONCE for both halves
  {
    const u16* srow = src + (size_t)(Nbase + t) * 64;
    char* drow = (char*)featB + t * 128;
    const int r7 = t & 7;
#pragma unroll
    for (int g = 0; g < 8; ++g) {
      short8b v = *reinterpret_cast<const short8b*>(srow + g * 8);
      float f[8];
#pragma unroll
      for (int j = 0; j < 8; ++j) {
        const int c = g * 8 + j;
        f[j] = fmaxf(fmaf(bf2f((u16)v[j]), scsh[c * 2], scsh[c * 2 + 1]), 0.f);
      }
      uint4 pk{cvtpk(f[0], f[1]), cvtpk(f[2], f[3]), cvtpk(f[4], f[5]), cvtpk(f[6], f[7])};
      *reinterpret_cast<uint4*>(drow + ((g ^ r7) << 4)) = pk;
    }
  }
  if (t < 8) *reinterpret_cast<uint4*>((char*)featB + 32768 + t * 16) = uint4{0, 0, 0, 0};

  const char* fB = (const char*)featB;
  const int swzA0 = (lk << 4) ^ ((lrow & 7) << 4);
  const int swzA1 = (64 | (lk << 4)) ^ ((lrow & 7) << 4);

  f32x4 acc[4][8];
  for (int oh = 0; oh < 2; ++oh) {
    // W tap1 -> regs
    uint4 r0, r1, r2, r3v;
    {
      const u16* wsrc = wp + 16384 + oh * 8192 + so * 64 + shalf * 32;
      r0 = *reinterpret_cast<const uint4*>(wsrc);
      r1 = *reinterpret_cast<const uint4*>(wsrc + 8);
      r2 = *reinterpret_cast<const uint4*>(wsrc + 16);
      r3v = *reinterpret_cast<const uint4*>(wsrc + 24);
    }
    if (oh == 1) {
      // restage tap0 for half 1
      const u16* wsrc = wp + 8192 + so * 64 + shalf * 32;
      uint4 w0 = *reinterpret_cast<const uint4*>(wsrc);
      uint4 w1 = *reinterpret_cast<const uint4*>(wsrc + 8);
      uint4 w2 = *reinterpret_cast<const uint4*>(wsrc + 16);
      uint4 w3w = *reinterpret_cast<const uint4*>(wsrc + 24);
      char* dst = (char*)ldsW[0] + so * 128;
      const int gb = shalf * 4;
      *reinterpret_cast<uint4*>(dst + (((gb + 0) ^ so7) << 4)) = w0;
      *reinterpret_cast<uint4*>(dst + (((gb + 1) ^ so7) << 4)) = w1;
      *reinterpret_cast<uint4*>(dst + (((gb + 2) ^ so7) << 4)) = w2;
      *reinterpret_cast<uint4*>(dst + (((gb + 3) ^ so7) << 4)) = w3w;
    }
#pragma unroll
    for (int m = 0; m < 4; ++m)
#pragma unroll
      for (int n = 0; n < 8; ++n) acc[m][n] = f32x4{0.f, 0.f, 0.f, 0.f};
    __syncthreads();

#pragma unroll
    for (int tap = 0; tap < 9; ++tap) {
      const int cur = tap & 1;
      const char* lW = (const char*)ldsW[cur];
      short8b aw0[4], aw1[4];
#pragma unroll
      for (int m = 0; m < 4; ++m) {
        const int rowoff = (wm * 64 + m * 16 + lrow) << 7;
        aw0[m] = *reinterpret_cast<const short8b*>(lW + rowoff + swzA0);
        aw1[m] = *reinterpret_cast<const short8b*>(lW + rowoff + swzA1);
      }
#pragma unroll
      for (int n = 0; n < 8; ++n) {
        int ad0 = ((wn * 128 + n * 16) << 7) + rel[tap];
        ad0 = ad0 < 32768 ? ad0 : 32768;
        const int swz = (ad0 >> 3) & 0x70;
        short8b bf0 = *reinterpret_cast<const short8b*>(fB + ad0 + ((lk << 4) ^ swz));
        short8b bf1 = *reinterpret_cast<const short8b*>(fB + ad0 + ((64 | (lk << 4)) ^ swz));
#pragma unroll
        for (int m = 0; m < 4; ++m) {
          acc[m][n] = __builtin_amdgcn_mfma_f32_16x16x32_bf16(aw0[m], bf0, acc[m][n], 0, 0, 0);
          acc[m][n] = __builtin_amdgcn_mfma_f32_16x16x32_bf16(aw1[m], bf1, acc[m][n], 0, 0, 0);
        }
      }
      if (tap < 8) {
        char* dst = (char*)ldsW[cur ^ 1] + so * 128;
        const int gb = shalf * 4;
        *reinterpret_cast<uint4*>(dst + (((gb + 0) ^ so7) << 4)) = r0;
        *reinterpret_cast<uint4*>(dst + (((gb + 1) ^ so7) << 4)) = r1;
        *reinterpret_cast<uint4*>(dst + (((gb + 2) ^ so7) << 4)) = r2;
        *reinterpret_cast<uint4*>(dst + (((gb + 3) ^ so7) << 4)) = r3v;
        if (tap < 7) {
          const u16* wsrc = wp + (tap + 2) * 16384 + oh * 8192 + so * 64 + shalf * 32;
          r0 = *reinterpret_cast<const uint4*>(wsrc);
          r1 = *reinterpret_cast<const uint4*>(wsrc + 8);
          r2 = *reinterpret_cast<const uint4*>(wsrc + 16);
          r3v = *reinterpret_cast<const uint4*>(wsrc + 24);
        }
      }
      __syncthreads();
    }

    if (oh == 0) {
      // half A -> bf16 scratch y3a[wg][o 128][col 256]
#pragma unroll
      for (int m = 0; m < 4; ++m) {
        const int ol = wm * 64 + m * 16 + lk * 4;
#pragma unroll
        for (int n = 0; n < 8; ++n) {
          const int col = wn * 128 + n * 16 + lrow;
          u16* dst = y3a + (size_t)wg * 32768 + (size_t)ol * 256 + col;
#pragma unroll
          for (int r = 0; r < 4; ++r) dst[r * 256] = f2bf(acc[m][n][r]);
        }
      }
    }
    // stats partials for this half
    pst[t] = 0.f;
    __syncthreads();
#pragma unroll
    for (int m = 0; m < 4; ++m) {
#pragma unroll
      for (int r = 0; r < 4; ++r) {
        float s = 0.f, s2 = 0.f;
#pragma unroll
        for (int n = 0; n < 8; ++n) {
          float v = acc[m][n][r];
          s += v; s2 = fmaf(v, v, s2);
        }
        s += __shfl_xor(s, 1); s2 += __shfl_xor(s2, 1);
        s += __shfl_xor(s, 2); s2 += __shfl_xor(s2, 2);
        s += __shfl_xor(s, 4); s2 += __shfl_xor(s2, 4);
        s += __shfl_xor(s, 8); s2 += __shfl_xor(s2, 8);
        if (lrow == 0) {
          const int ch = wm * 64 + m * 16 + lk * 4 + r;
          atomicAdd(&pst[ch], s);
          atomicAdd(&pst[128 + ch], s2);
        }
      }
    }
    __syncthreads();
    p3[(size_t)wg * 512 + oh * 256 + t] = pst[t];
    __syncthreads();
  }

  __threadfence();
  cooperative_groups::this_grid().sync();

  // reduce: this WG owns idx = wg (0..511)
  {
    const int idx = wg;
    float s = p3[(size_t)t * 512 + idx] + p3[(size_t)(t + 256) * 512 + idx];
#pragma unroll
    for (int off = 32; off > 0; off >>= 1) s += __shfl_down(s, off);
    if (lane == 0) pst[w] = s;
    __syncthreads();
    if (t == 0) {
      const int half = idx >> 8, kind = (idx >> 7) & 1, chl = idx & 127;
      acc3[kind * 256 + half * 128 + chl] = pst[0] + pst[1] + pst[2] + pst[3];
    }
  }
  __threadfence();
  cooperative_groups::this_grid().sync();

  // BN3+relu: half B from registers (o 128..255)
#pragma unroll
  for (int m = 0; m < 4; ++m) {
#pragma unroll
    for (int r = 0; r < 4; ++r) {
      const int o = 128 + wm * 64 + m * 16 + lk * 4 + r;
      float sh; const float sc = bn_scale(acc3, g3, b3, 256, o, sh);
#pragma unroll
      for (int n = 0; n < 8; ++n) {
        const int colg = Nbase + wn * 128 + n * 16 + lrow;
        out[(size_t)(colg >> 4) * 4096 + o * 16 + (colg & 15)] =
            fmaxf(fmaf(acc[m][n][r], sc, sh), 0.f);
      }
    }
  }
  // BN3+relu: half A from y3a (o 0..127), fully coalesced both sides
  {
    const int o = t >> 1, p8 = (t & 1) * 8;
    float sh; const float sc = bn_scale(acc3, g3, b3, 256, o, sh);
    const u16* srcA = y3a + (size_t)wg * 32768 + (size_t)o * 256;
#pragma unroll
    for (int bb = 0; bb < 16; ++bb) {
      short8b v = *reinterpret_cast<const short8b*>(srcA + bb * 16 + p8);
      float4 f0, f1;
      f0.x = fmaxf(fmaf(bf2f((u16)v[0]), sc, sh), 0.f);
      f0.y = fmaxf(fmaf(bf2f((u16)v[1]), sc, sh), 0.f);
      f0.z = fmaxf(fmaf(bf2f((u16)v[2]), sc, sh), 0.f);
      f0.w = fmaxf(fmaf(bf2f((u16)v[3]), sc, sh), 0.f);
      f1.x = fmaxf(fmaf(bf2f((u16)v[4]), sc, sh), 0.f);
      f1.y = fmaxf(fmaf(bf2f((u16)v[5]), sc, sh), 0.f);
      f1.z = fmaxf(fmaf(bf2f((u16)v[6]), sc, sh), 0.f);
      f1.w = fmaxf(fmaf(bf2f((u16)v[7]), sc, sh), 0.f);
      float* dsto = out + (size_t)(wg * 16 + bb) * 4096 + o * 16 + p8;
      *reinterpret_cast<float4*>(dsto) = f0;
      *reinterpret_cast<float4*>(dsto + 4) = f1;
    }
  }
}

// ---------- FALLBACK split path (identical to round 5) ----------
__global__ __launch_bounds__(256, 2) void conv3_kernel(const u16* __restrict__ src,
                                                       const u16* __restrict__ wp,
                                                       const float* __restrict__ acc2,
                                                       const float* __restrict__ g2,
                                                       const float* __restrict__ b2,
                                                       u16* __restrict__ y3b,
                                                       float* __restrict__ partials3) {
  __shared__ __align__(16) u16 featB[257 * 64];
  __shared__ __align__(16) u16 ldsW[2][128 * 64];
  __shared__ float scsh[128];
  const int t = threadIdx.x;
  const int lane = t & 63, w = t >> 6;
  const int lrow = lane & 15, lk = lane >> 4;
  const int wm = w >> 1, wn = w & 1;
  const int Nbase = blockIdx.x * 256;
  const int ohalf = blockIdx.y;

  int rel[9];
  {
    const int pi = lrow >> 2, pj = lrow & 3;
#pragma unroll
    for (int tap = 0; tap < 9; ++tap) {
      const int ti = tap / 3, tj = tap - ti * 3;
      int si = pi + ti - 1, sj = pj + tj - 1;
      bool valid = ((unsigned)si < 4u) && ((unsigned)sj < 4u);
      rel[tap] = valid ? ((si * 4 + sj) << 7) : (1 << 24);
    }
  }
  if (t < 64) {
    float sh; float sc = bn_scale(acc2, g2, b2, 64, t, sh);
    scsh[t * 2] = sc; scsh[t * 2 + 1] = sh;
  }
  const int so = t >> 1, shalf = t & 1, so7 = so & 7;
  {
    const u16* wsrc = wp + ohalf * 8192 + so * 64 + shalf * 32;
    uint4 w0 = *reinterpret_cast<const uint4*>(wsrc);
    uint4 w1 = *reinterpret_cast<const uint4*>(wsrc + 8);
    uint4 w2 = *reinterpret_cast<const uint4*>(wsrc + 16);
    uint4 w3v = *reinterpret_cast<const uint4*>(wsrc + 24);
    char* dst = (char*)ldsW[0] + so * 128;
    const int gb = shalf * 4;
    *reinterpret_cast<uint4*>(dst + (((gb + 0) ^ so7) << 4)) = w0;
    *reinterpret_cast<uint4*>(dst + (((gb + 1) ^ so7) << 4)) = w1;
    *reinterpret_cast<uint4*>(dst + (((gb + 2) ^ so7) << 4)) = w2;
    *reinterpret_cast<uint4*>(dst + (((gb + 3) ^ so7) << 4)) = w3v;
  }
  __syncthreads();
  {
    const u16* srow = src + (size_t)(Nbase + t) * 64;
    char* drow = (char*)featB + t * 128;
    const int r7 = t & 7;
#pragma unroll
    for (int g = 0; g < 8; ++g) {
      short8b v = *reinterpret_cast<const short8b*>(srow + g * 8);
      float f[8];
#pragma unroll
      for (int j = 0; j < 8; ++j) {
        const int c = g * 8 + j;
        f[j] = fmaxf(fmaf(bf2f((u16)v[j]), scsh[c * 2], scsh[c * 2 + 1]), 0.f);
      }
      uint4 pk{cvtpk(f[0], f[1]), cvtpk(f[2], f[3]), cvtpk(f[4], f[5]), cvtpk(f[6], f[7])};
      *reinterpret_cast<uint4*>(drow + ((g ^ r7) << 4)) = pk;
    }
  }
  if (t < 8) *reinterpret_cast<uint4*>((char*)featB + 32768 + t * 16) = uint4{0, 0, 0, 0};
  uint4 r0, r1, r2, r3v;
  {
    const u16* wsrc = wp + 16384 + ohalf * 8192 + so * 64 + shalf * 32;
    r0 = *reinterpret_cast<const uint4*>(wsrc);
    r1 = *reinterpret_cast<const uint4*>(wsrc + 8);
    r2 = *reinterpret_cast<const uint4*>(wsrc + 16);
    r3v = *reinterpret_cast<const uint4*>(wsrc + 24);
  }
  __syncthreads();
  f32x4 acc[4][8] = {};
  const char* fB = (const char*)featB;
  const int swzA0 = (lk << 4) ^ ((lrow & 7) << 4);
  const int swzA1 = (64 | (lk << 4)) ^ ((lrow & 7) << 4);
#pragma unroll
  for (int tap = 0; tap < 9; ++tap) {
    const int cur = tap & 1;
    const char* lW = (const char*)ldsW[cur];
    short8b aw0[4], aw1[4];
#pragma unroll
    for (int m = 0; m < 4; ++m) {
      const int rowoff = (wm * 64 + m * 16 + lrow) << 7;
      aw0[m] = *reinterpret_cast<const short8b*>(lW + rowoff + swzA0);
      aw1[m] = *reinterpret_cast<const short8b*>(lW + rowoff + swzA1);
    }
#pragma unroll
    for (int n = 0; n < 8; ++n) {
      int ad0 = ((wn * 128 + n * 16) << 7) + rel[tap];
      ad0 = ad0 < 32768 ? ad0 : 32768;
      const int swz = (ad0 >> 3) & 0x70;
      short8b bf0 = *reinterpret_cast<const short8b*>(fB + ad0 + ((lk << 4) ^ swz));
      short8b bf1 = *reinterpret_cast<const short8b*>(fB + ad0 + ((64 | (lk << 4)) ^ swz));
#pragma unroll
      for (int m = 0; m < 4; ++m) {
        acc[m][n] = __builtin_amdgcn_mfma_f32_16x16x32_bf16(aw0[m], bf0, acc[m][n], 0, 0, 0);
        acc[m][n] = __builtin_amdgcn_mfma_f32_16x16x32_bf16(aw1[m], bf1, acc[m][n], 0, 0, 0);
      }
    }
    if (tap < 8) {
      char* dst = (char*)ldsW[cur ^ 1] + so * 128;
      const int gb = shalf * 4;
      *reinterpret_cast<uint4*>(dst + (((gb + 0) ^ so7) << 4)) = r0;
      *reinterpret_cast<uint4*>(dst + (((gb + 1) ^ so7) << 4)) = r1;
      *reinterpret_cast<uint4*>(dst + (((gb + 2) ^ so7) << 4)) = r2;
      *reinterpret_cast<uint4*>(dst + (((gb + 3) ^ so7) << 4)) = r3v;
      if (tap < 7) {
        const u16* wsrc = wp + (tap + 2) * 16384 + ohalf * 8192 + so * 64 + shalf * 32;
        r0 = *reinterpret_cast<const uint4*>(wsrc);
        r1 = *reinterpret_cast<const uint4*>(wsrc + 8);
        r2 = *reinterpret_cast<const uint4*>(wsrc + 16);
        r3v = *reinterpret_cast<const uint4*>(wsrc + 24);
      }
    }
    __syncthreads();
  }
#pragma unroll
  for (int m = 0; m < 4; ++m) {
    const int o = ohalf * 128 + wm * 64 + m * 16 + lk * 4;
#pragma unroll
    for (int n = 0; n < 8; ++n) {
      const int colg = Nbase + wn * 128 + n * 16 + lrow;
      const int b = colg >> 4, p = colg & 15;
      u16* dst = y3b + (size_t)b * 4096 + (size_t)o * 16 + p;
#pragma unroll
      for (int r = 0; r < 4; ++r) dst[r * 16] = f2bf(acc[m][n][r]);
    }
  }
  float* pst = reinterpret_cast<float*>(featB);
  pst[t] = 0.f;
  __syncthreads();
#pragma unroll
  for (int m = 0; m < 4; ++m) {
#pragma unroll
    for (int r = 0; r < 4; ++r) {
      float s = 0.f, s2 = 0.f;
#pragma unroll
      for (int n = 0; n < 8; ++n) {
        float v = acc[m][n][r];
        s += v; s2 = fmaf(v, v, s2);
      }
      s += __shfl_xor(s, 1); s2 += __shfl_xor(s2, 1);
      s += __shfl_xor(s, 2); s2 += __shfl_xor(s2, 2);
      s += __shfl_xor(s, 4); s2 += __shfl_xor(s2, 4);
      s += __shfl_xor(s, 8); s2 += __shfl_xor(s2, 8);
      if (lrow == 0) {
        const int ch = wm * 64 + m * 16 + lk * 4 + r;
        atomicAdd(&pst[ch], s);
        atomicAdd(&pst[128 + ch], s2);
      }
    }
  }
  __syncthreads();
  partials3[((size_t)(ohalf * 512 + blockIdx.x)) * 256 + t] = pst[t];
}

__global__ __launch_bounds__(256) void reduce3_kernel(const float* __restrict__ p,
                                                      float* __restrict__ acc3) {
  const int c2 = blockIdx.x, t = threadIdx.x;
  const int kind = c2 >> 8, c = c2 & 255;
  const int h = c >> 7, chl = c & 127;
  float s = 0.f;
  for (int i = t; i < 512; i += 256)
    s += p[((size_t)(h * 512 + i)) * 256 + kind * 128 + chl];
#pragma unroll
  for (int off = 32; off > 0; off >>= 1) s += __shfl_down(s, off);
  __shared__ float red[4];
  if ((t & 63) == 0) red[t >> 6] = s;
  __syncthreads();
  if (t == 0) acc3[kind * 256 + c] = red[0] + red[1] + red[2] + red[3];
}

__global__ __launch_bounds__(256) void final_kernel(const u16* __restrict__ y3b,
                                                    float* __restrict__ out,
                                                    const float* __restrict__ acc3,
                                                    const float* __restrict__ g3,
                                                    const float* __restrict__ b3) {
  const size_t i = ((size_t)blockIdx.x * 256 + threadIdx.x) * 8;
  const int c = (int)((i >> 4) & 255);
  float sh; const float sc = bn_scale(acc3, g3, b3, 256, c, sh);
  short8b v = *reinterpret_cast<const short8b*>(y3b + i);
  float4 o0, o1;
  o0.x = fmaxf(fmaf(bf2f((u16)v[0]), sc, sh), 0.f);
  o0.y = fmaxf(fmaf(bf2f((u16)v[1]), sc, sh), 0.f);
  o0.z = fmaxf(fmaf(bf2f((u16)v[2]), sc, sh), 0.f);
  o0.w = fmaxf(fmaf(bf2f((u16)v[3]), sc, sh), 0.f);
  o1.x = fmaxf(fmaf(bf2f((u16)v[4]), sc, sh), 0.f);
  o1.y = fmaxf(fmaf(bf2f((u16)v[5]), sc, sh), 0.f);
  o1.z = fmaxf(fmaf(bf2f((u16)v[6]), sc, sh), 0.f);
  o1.w = fmaxf(fmaf(bf2f((u16)v[7]), sc, sh), 0.f);
  *reinterpret_cast<float4*>(out + i) = o0;
  *reinterpret_cast<float4*>(out + i + 4) = o1;
}

extern "C" void kernel_launch(void* const* d_in, const int* in_sizes, int n_in,
                              void* d_out, int out_size, void* d_ws, size_t ws_size,
                              hipStream_t stream) {
  const float* x   = (const float*)d_in[0];
  const float* w1  = (const float*)d_in[1];
  const float* g1  = (const float*)d_in[3];
  const float* bb1 = (const float*)d_in[4];
  const float* wq  = (const float*)d_in[5];
  const float* wk  = (const float*)d_in[6];
  const float* wv  = (const float*)d_in[7];
  const float* rw  = (const float*)d_in[8];
  const float* rh  = (const float*)d_in[9];
  const float* g2  = (const float*)d_in[10];
  const float* bb2 = (const float*)d_in[11];
  const float* w3  = (const float*)d_in[12];
  const float* g3  = (const float*)d_in[14];
  const float* bb3 = (const float*)d_in[15];
  float* out = (float*)d_out;
  float* ws  = (float*)d_ws;

  u16*   bufb   = (u16*)ws;                 // 8,388,608 u16
  u16*   y3     = bufb + 8388608;           // 33,554,432 u16 (coop uses first half as y3a)
  u16*   wp1    = y3 + 33554432;            // 46,080
  u16*   wp3    = wp1 + 46080;              // 147,456
  u16*   wqkvT  = wp3 + 147456;             // 16,384
  // u16 total = 42,152,960 -> 21,076,480 floats
  float* acc1   = ws + 21076480;            // 128
  float* acc2   = acc1 + 128;               // 128
  float* acc3   = acc2 + 128;               // 512
  float* part1  = acc3 + 512;               // 65,536
  float* part2  = part1 + 65536;            // 262,144
  float* part3  = part2 + 262144;           // 262,144 (coop: [512][512]; fallback: [1024][256])

  prep_kernel<<<820, 256, 0, stream>>>(w1, w3, wq, wk, wv, rw, rh, wp1, wp3, wqkvT);
  conv1_kernel<<<512, 256, 0, stream>>>(x, wp1, bufb, part1);
  reduce12_kernel<<<128, 256, 0, stream>>>(part1, acc1, 512);
  attn_kernel<<<2048, 256, 0, stream>>>(bufb, wqkvT, acc1, g1, bb1, part2);
  reduce12_kernel<<<128, 256, 0, stream>>>(part2, acc2, 2048);

  {
    const u16* srcb = bufb; const u16* wpc = wp3;
    void* args[] = {(void*)&srcb, (void*)&wpc, (void*)&acc2, (void*)&g2, (void*)&bb2,
                    (void*)&g3, (void*)&bb3, (void*)&out, (void*)&y3, (void*)&part3,
                    (void*)&acc3};
    hipError_t e = hipLaunchCooperativeKernel((const void*)conv3_coop, dim3(512), dim3(256),
                                              args, 0, stream);
    if (e != hipSuccess) {
      (void)hipGetLastError();
      conv3_kernel<<<dim3(512, 2), 256, 0, stream>>>(bufb, wp3, acc2, g2, bb2, y3, part3);
      reduce3_kernel<<<512, 256, 0, stream>>>(part3, acc3);
      final_kernel<<<16384, 256, 0, stream>>>(y3, out, acc3, g3, bb3);
    }
  }
}

// Round 7
// 159.947 us; speedup vs baseline: 2.7793x; 2.7793x over previous
//
#include <hip/hip_runtime.h>
#include <stdint.h>

// BotBlock pipeline, MFMA version (round 7).
// Block space: 8192 independent 4x4x64 blocks (raw-reshape semantics).
// buf (ws) bf16 NHWC block space: buf[row*64 + c], row = b*16 + p.
// Convs = im2col GEMMs, K = 576 (9 taps x 64 ch), bf16 MFMA 16x16x32, fp32 acc.
// Split conv3 path (coop grid-sync experiment REVERTED: 365us vs 52us split —
// grid sync rendezvous + register state across sync kills occupancy/MFMA).
// attn: qkv + folded rel-logits via one MFMA GEMM (16 tiles), f32 LDS core.

#define EPSV 1e-5f
#define INV_N (1.0f / 131072.0f)

typedef unsigned short u16;
typedef __attribute__((ext_vector_type(8))) short short8b;  // 8 bf16
typedef __attribute__((ext_vector_type(4))) float f32x4;

__device__ __forceinline__ u16 f2bf(float f) {
  unsigned u = __float_as_uint(f);
  u += 0x7fffu + ((u >> 16) & 1u);
  return (u16)(u >> 16);
}
__device__ __forceinline__ float bf2f(u16 h) {
  return __uint_as_float((unsigned)h << 16);
}
__device__ __forceinline__ unsigned cvtpk(float lo, float hi) {
  unsigned r;
  asm("v_cvt_pk_bf16_f32 %0, %1, %2" : "=v"(r) : "v"(lo), "v"(hi));
  return r;
}

__device__ __forceinline__ float bn_scale(const float* __restrict__ acc,
                                          const float* __restrict__ gam,
                                          const float* __restrict__ bet,
                                          int C, int c, float& shift) {
  float S = acc[c], S2 = acc[C + c];
  float mean = S * INV_N;
  float var  = S2 * INV_N - mean * mean;
  float rstd = rsqrtf(var + EPSV);
  float sc = gam[c] * rstd;
  shift = bet[c] - mean * sc;
  return sc;
}

// ---------- prep: conv1 w -> [18][64][40]; conv3 w -> [9][256][64]; qkv+rel -> [256][64] ----------
__global__ __launch_bounds__(256) void prep_kernel(const float* __restrict__ w1,
                                                   const float* __restrict__ w3,
                                                   const float* __restrict__ wq,
                                                   const float* __restrict__ wk,
                                                   const float* __restrict__ wv,
                                                   const float* __restrict__ relw,
                                                   const float* __restrict__ relh,
                                                   u16* __restrict__ wp1,
                                                   u16* __restrict__ wp3,
                                                   u16* __restrict__ wqkvT) {
  int i = blockIdx.x * 256 + threadIdx.x;
  const int tot1 = 18 * 64 * 40;       // 46080
  const int tot3 = 9 * 256 * 64;       // 147456
  if (i < tot1) {
    int ch = i / (64 * 40); int r = i - ch * 64 * 40; int o = r / 40; int kk = r - o * 40;
    float v = 0.f;
    if (kk < 32) { int k = ch * 32 + kk; int tap = k >> 6; int c = k & 63;
                   v = w1[o * 576 + c * 9 + tap]; }
    wp1[i] = f2bf(v);
  } else if (i < tot1 + tot3) {
    int j = i - tot1;
    int tap = j >> 14; int r = j & 16383; int o = r >> 6; int c = r & 63;
    wp3[j] = f2bf(w3[o * 576 + c * 9 + tap]);
  } else if (i < tot1 + tot3 + 192 * 64) {
    int j = i - tot1 - tot3;
    int oc = j >> 6, c = j & 63;
    const float* src = (oc < 64) ? wq : (oc < 128) ? wk : wv;
    wqkvT[j] = f2bf(src[(c << 6) + (oc & 63)]);
  } else if (i < tot1 + tot3 + 192 * 64 + 4096) {
    int j = i - tot1 - tot3 - 192 * 64;  // 0..4095
    int c = j & 63; int col = (j >> 6) & 31; int tbl = j >> 11;
    int n = col >> 3, m = col & 7;
    float v = 0.f;
    if (m < 7) {
      const float* rel = tbl ? relh : relw;
#pragma unroll
      for (int d = 0; d < 16; ++d) v += wq[c * 64 + n * 16 + d] * rel[m * 16 + d];
    }
    wqkvT[(192 + tbl * 32 + col) * 64 + c] = f2bf(v);
  }
}

// ---------- conv1: x (NCHW blocks, fp32) -> buf (NHWC bf16) + fused stats1 ----------
__global__ __launch_bounds__(256) void conv1_kernel(const float* __restrict__ x,
                                                    const u16* __restrict__ wp,
                                                    u16* __restrict__ bufb,
                                                    float* __restrict__ partials1) {
  __shared__ __align__(16) char featA[257 * 128];   // bf16 [row][64ch], swizzled; row 256 = zeros
  __shared__ __align__(16) char ldsW[2][64 * 80];   // [o][40 bf16] per 32-k chunk
  const int t = threadIdx.x;
  const int lane = t & 63, w = t >> 6;
  const int lrow = lane & 15, lk = lane >> 4;
  const int wm = w >> 1, wn = w & 1;                // wave tile: 128 rows x 32 o
  const size_t Mbase = (size_t)blockIdx.x * 256;

  int rel[9];
  {
    const int pi = lrow >> 2, pj = lrow & 3;
#pragma unroll
    for (int tap = 0; tap < 9; ++tap) {
      const int ti = tap / 3, tj = tap - ti * 3;
      int si = pi + ti - 1, sj = pj + tj - 1;
      bool valid = ((unsigned)si < 4u) && ((unsigned)sj < 4u);
      rel[tap] = valid ? ((si * 4 + sj) << 7) : (1 << 24);
    }
  }

  // staging: thread -> c-pair cp (0..31), p-half ph (0..7); pair-packed b32 LDS writes
  {
    const int cp = t >> 3, ph = t & 7;
    const int gsw = ((cp >> 2) << 4) | ((cp & 3) << 2);   // granule-col part of swizzle
#pragma unroll
    for (int i = 0; i < 16; ++i) {
      const float* bp = x + Mbase * 64 + i * 1024 + cp * 32 + ph * 2;
      float2 a = *reinterpret_cast<const float2*>(bp);
      float2 b = *reinterpret_cast<const float2*>(bp + 16);
#pragma unroll
      for (int j = 0; j < 2; ++j) {
        const int row = i * 16 + ph * 2 + j;
        unsigned pk = cvtpk(j ? a.y : a.x, j ? b.y : b.x);
        const int byte = row * 128 + (gsw ^ ((row & 7) << 4));
        *reinterpret_cast<unsigned*>(featA + byte) = pk;
      }
    }
  }
  if (t < 8) *reinterpret_cast<uint4*>(featA + 256 * 128 + t * 16) = uint4{0, 0, 0, 0};

  uint4 s0, s1;
  {
    const u16* sp = wp;
    s0 = *reinterpret_cast<const uint4*>(sp + (size_t)t * 8);
    if (t < 64) s1 = *reinterpret_cast<const uint4*>(sp + (size_t)(t + 256) * 8);
    *reinterpret_cast<uint4*>(ldsW[0] + t * 16) = s0;
    if (t < 64) *reinterpret_cast<uint4*>(ldsW[0] + (t + 256) * 16) = s1;
  }
  __syncthreads();

  f32x4 acc[8][2] = {};
#pragma unroll
  for (int chn = 0; chn < 18; ++chn) {
    const int cur = chn & 1;
    const int tap = chn >> 1, kk = chn & 1;
    if (chn + 1 < 18) {
      const u16* sp = wp + (chn + 1) * 2560;
      s0 = *reinterpret_cast<const uint4*>(sp + (size_t)t * 8);
      if (t < 64) s1 = *reinterpret_cast<const uint4*>(sp + (size_t)(t + 256) * 8);
    }
    const int kkg = (kk << 6) | (lk << 4);
    short8b bw[2];
#pragma unroll
    for (int n = 0; n < 2; ++n)
      bw[n] = *reinterpret_cast<const short8b*>(ldsW[cur] + (wn * 32 + n * 16 + lrow) * 80 + lk * 16);
#pragma unroll
    for (int m = 0; m < 8; ++m) {
      int ad = ((wm * 128 + m * 16) << 7) + rel[tap];
      ad = ad < 32768 ? ad : 32768;
      ad += (kkg ^ ((ad >> 3) & 0x70));
      short8b af = *reinterpret_cast<const short8b*>(featA + ad);
#pragma unroll
      for (int n = 0; n < 2; ++n)
        acc[m][n] = __builtin_amdgcn_mfma_f32_16x16x32_bf16(af, bw[n], acc[m][n], 0, 0, 0);
    }
    if (chn + 1 < 18) {
      *reinterpret_cast<uint4*>(ldsW[cur ^ 1] + t * 16) = s0;
      if (t < 64) *reinterpret_cast<uint4*>(ldsW[cur ^ 1] + (t + 256) * 16) = s1;
    }
    __syncthreads();
  }

  // bf16 NHWC stores
#pragma unroll
  for (int m = 0; m < 8; ++m) {
    const size_t rowg0 = Mbase + wm * 128 + m * 16 + lk * 4;
#pragma unroll
    for (int n = 0; n < 2; ++n) {
      const int o = wn * 32 + n * 16 + lrow;
#pragma unroll
      for (int r = 0; r < 4; ++r)
        bufb[(rowg0 + r) * 64 + o] = f2bf(acc[m][n][r]);
    }
  }

  // fused stats1 (channel = o)
  float* pst = reinterpret_cast<float*>(featA);    // [S 64][S2 64]
  if (t < 128) pst[t] = 0.f;
  __syncthreads();
#pragma unroll
  for (int n = 0; n < 2; ++n) {
    float s = 0.f, s2 = 0.f;
#pragma unroll
    for (int m = 0; m < 8; ++m)
#pragma unroll
      for (int r = 0; r < 4; ++r) {
        float v = acc[m][n][r];
        s += v; s2 = fmaf(v, v, s2);
      }
    s += __shfl_xor(s, 16); s2 += __shfl_xor(s2, 16);
    s += __shfl_xor(s, 32); s2 += __shfl_xor(s2, 32);
    if (lk == 0) {
      const int o = wn * 32 + n * 16 + lrow;
      atomicAdd(&pst[o], s);
      atomicAdd(&pst[64 + o], s2);
    }
  }
  __syncthreads();
  if (t < 128) partials1[(size_t)blockIdx.x * 128 + t] = pst[t];
}

// ---------- generic partial reduce for stats1/stats2 (stride 128) ----------
__global__ __launch_bounds__(256) void reduce12_kernel(const float* __restrict__ p,
                                                       float* __restrict__ acc, int nrows) {
  const int c = blockIdx.x, t = threadIdx.x;
  float s = 0.f;
  for (int i = t; i < nrows; i += 256) s += p[(size_t)i * 128 + c];
#pragma unroll
  for (int off = 32; off > 0; off >>= 1) s += __shfl_down(s, off);
  __shared__ float red[4];
  if ((t & 63) == 0) red[t >> 6] = s;
  __syncthreads();
  if (t == 0) acc[c] = red[0] + red[1] + red[2] + red[3];
}

// ---------- attn: BN1+relu -> qkv+rel (MFMA) -> attn core (f32 LDS) -> buf bf16 + stats2 ----------
__global__ __launch_bounds__(256) void attn_kernel(u16* __restrict__ buf,
                                                   const u16* __restrict__ wqkvT,
                                                   const float* __restrict__ acc1,
                                                   const float* __restrict__ g1,
                                                   const float* __restrict__ b1,
                                                   float* __restrict__ partials2) {
  __shared__ float scsh[64][2];
  __shared__ float pstA[128];
  __shared__ __align__(16) u16 feat_l[4][1024];
  __shared__ __align__(16) float qkvf[4][3200];
  __shared__ __align__(16) float relLs[4][1152];
  const int t = threadIdx.x, u = t >> 6, lane = t & 63;
  const size_t b = (size_t)blockIdx.x * 4 + u;
  float* Wf = qkvf[u];
  float* rL = relLs[u];

  if (t < 64) {
    float sh; float sc = bn_scale(acc1, g1, b1, 64, t, sh);
    scsh[t][0] = sc; scsh[t][1] = sh;
  }
  if (t < 128) pstA[t] = 0.f;
  __syncthreads();

  // ---- stage feat (BN1+relu on bf16 buf) ----
  {
    const int pos = lane >> 2, cq = lane & 3;
    const u16* src = buf + b * 1024 + pos * 64 + cq * 16;
    short8b v0 = *reinterpret_cast<const short8b*>(src);
    short8b v1 = *reinterpret_cast<const short8b*>(src + 8);
    float f[16];
#pragma unroll
    for (int j = 0; j < 8; ++j) {
      const int c0 = cq * 16 + j, c1 = cq * 16 + 8 + j;
      f[j]     = fmaxf(fmaf(bf2f((u16)v0[j]), scsh[c0][0], scsh[c0][1]), 0.f);
      f[8 + j] = fmaxf(fmaf(bf2f((u16)v1[j]), scsh[c1][0], scsh[c1][1]), 0.f);
    }
    uint4 q0{cvtpk(f[0], f[1]), cvtpk(f[2], f[3]), cvtpk(f[4], f[5]), cvtpk(f[6], f[7])};
    uint4 q1{cvtpk(f[8], f[9]), cvtpk(f[10], f[11]), cvtpk(f[12], f[13]), cvtpk(f[14], f[15])};
    const int g0 = (cq * 2) ^ (pos & 7), g1g = (cq * 2 + 1) ^ (pos & 7);
    *reinterpret_cast<uint4*>(&feat_l[u][pos * 64 + g0 * 8]) = q0;
    *reinterpret_cast<uint4*>(&feat_l[u][pos * 64 + g1g * 8]) = q1;
  }

  // ---- qkv + rel via MFMA (16 col tiles) ----
  const int dq = lane & 15, lk = lane >> 4;
  short8b afr[2];
#pragma unroll
  for (int ch = 0; ch < 2; ++ch) {
    const int kg = ch * 4 + lk;
    afr[ch] = *reinterpret_cast<const short8b*>(&feat_l[u][dq * 64 + ((kg ^ (dq & 7)) * 8)]);
  }
#pragma unroll
  for (int ct = 0; ct < 16; ++ct) {
    f32x4 d = {0.f, 0.f, 0.f, 0.f};
#pragma unroll
    for (int ch = 0; ch < 2; ++ch) {
      short8b bfr = *reinterpret_cast<const short8b*>(&wqkvT[(ct * 16 + dq) * 64 + ch * 32 + lk * 8]);
      d = __builtin_amdgcn_mfma_f32_16x16x32_bf16(afr[ch], bfr, d, 0, 0, 0);
    }
    if (ct < 4) {
      float* dst = Wf + ct * 272;
#pragma unroll
      for (int r = 0; r < 4; ++r) dst[(lk * 4 + r) * 17 + dq] = d[r] * 0.25f;
    } else if (ct < 12) {
      float* dst = (ct < 8) ? (Wf + 1088 + (ct - 4) * 264) : (Wf + 2144 + (ct - 8) * 264);
      const int cp = dq ^ (lk << 2);
#pragma unroll
      for (int r = 0; r < 4; ++r) dst[(lk * 4 + r) * 16 + cp] = d[r];
    } else {
      const int rc = ct - 12, tbl = rc >> 1;
      const int nn = ((rc & 1) << 1) | (dq >> 3), mm = dq & 7;
      float* dst = rL + tbl * 576 + nn * 144 + mm;
#pragma unroll
      for (int r = 0; r < 4; ++r) dst[(lk * 4 + r) * 9] = d[r] * 0.25f;
    }
  }

  // ---- attention core: thread = (head n=lk, query pos qp=dq) ----
  const int n = lk, qp = dq;
  const int qi = qp >> 2, qj = qp & 3;
  float q_[16];
  {
    const float* qb = Wf + n * 272 + qp * 17;
#pragma unroll
    for (int d2 = 0; d2 < 16; ++d2) q_[d2] = qb[d2];
  }
  float rwq[4], rhq[4];
  {
    const float* rw = rL + n * 144 + qp * 9 + (3 - qj);
    const float* rh = rL + 576 + n * 144 + qp * 9 + (3 - qi);
#pragma unroll
    for (int k = 0; k < 4; ++k) { rwq[k] = rw[k]; rhq[k] = rh[k]; }
  }
  float lo[16]; float mx = -1e30f;
  const float* kbase = Wf + 1088 + n * 264;
#pragma unroll
  for (int kp = 0; kp < 16; ++kp) {
    const float4* kr = reinterpret_cast<const float4*>(kbase + kp * 16);
    float s = rwq[kp & 3] + rhq[kp >> 2];
#pragma unroll
    for (int g = 0; g < 4; ++g) {
      float4 kv = kr[g];
      const int lg = (g ^ (kp >> 2)) * 4;
      s = fmaf(q_[lg], kv.x, s); s = fmaf(q_[lg + 1], kv.y, s);
      s = fmaf(q_[lg + 2], kv.z, s); s = fmaf(q_[lg + 3], kv.w, s);
    }
    lo[kp] = s; mx = fmaxf(mx, s);
  }
  float ssum = 0.f;
#pragma unroll
  for (int kp = 0; kp < 16; ++kp) { float e = __expf(lo[kp] - mx); lo[kp] = e; ssum += e; }
  const float inv = 1.0f / ssum;
  float ov[16];
#pragma unroll
  for (int j = 0; j < 16; ++j) ov[j] = 0.f;
  const float* vbase = Wf + 2144 + n * 264;
#pragma unroll
  for (int kp = 0; kp < 16; ++kp) {
    const float4* vr = reinterpret_cast<const float4*>(vbase + kp * 16);
    const float wgt = lo[kp];
#pragma unroll
    for (int g = 0; g < 4; ++g) {
      float4 vv = vr[g];
      const int lg = (g ^ (kp >> 2)) * 4;
      ov[lg] = fmaf(wgt, vv.x, ov[lg]);
      ov[lg + 1] = fmaf(wgt, vv.y, ov[lg + 1]);
      ov[lg + 2] = fmaf(wgt, vv.z, ov[lg + 2]);
      ov[lg + 3] = fmaf(wgt, vv.w, ov[lg + 3]);
    }
  }
#pragma unroll
  for (int j = 0; j < 16; ++j) ov[j] *= inv;

  // bf16 output write (cvt_pk packed)
  {
    uint4 o0{cvtpk(ov[0], ov[1]), cvtpk(ov[2], ov[3]), cvtpk(ov[4], ov[5]), cvtpk(ov[6], ov[7])};
    uint4 o1{cvtpk(ov[8], ov[9]), cvtpk(ov[10], ov[11]), cvtpk(ov[12], ov[13]), cvtpk(ov[14], ov[15])};
    u16* dstb = buf + b * 1024 + qp * 64 + (n << 4);
    *reinterpret_cast<uint4*>(dstb) = o0;
    *reinterpret_cast<uint4*>(dstb + 8) = o1;
  }

  // ---- fused stats2: per-wave LDS transpose (reuse Wf), column sums ----
  {
    float* fl = Wf;                                       // [16 pos][69]
#pragma unroll
    for (int j = 0; j < 16; ++j) fl[qp * 69 + n * 16 + j] = ov[j];
    const int c = lane;
    float s = 0.f, s2 = 0.f;
#pragma unroll
    for (int pos = 0; pos < 16; ++pos) {
      float v = fl[pos * 69 + c];
      s += v; s2 = fmaf(v, v, s2);
    }
    atomicAdd(&pstA[c], s);
    atomicAdd(&pstA[64 + c], s2);
  }
  __syncthreads();
  if (t < 128) partials2[(size_t)blockIdx.x * 128 + t] = pstA[t];
}

// ---------- conv3: BN2+relu(buf bf16 NHWC) -> y3b (bf16 NCHW) + fused stats3 ----------
__global__ __launch_bounds__(256, 2) void conv3_kernel(const u16* __restrict__ src,
                                                       const u16* __restrict__ wp,
                                                       const float* __restrict__ acc2,
                                                       const float* __restrict__ g2,
                                                       const float* __restrict__ b2,
                                                       u16* __restrict__ y3b,
                                                       float* __restrict__ partials3) {
  __shared__ __align__(16) u16 featB[257 * 64];
  __shared__ __align__(16) u16 ldsW[2][128 * 64];
  __shared__ float scsh[128];
  const int t = threadIdx.x;
  const int lane = t & 63, w = t >> 6;
  const int lrow = lane & 15, lk = lane >> 4;
  const int wm = w >> 1, wn = w & 1;
  const int Nbase = blockIdx.x * 256;
  const int ohalf = blockIdx.y;

  int rel[9];
  {
    const int pi = lrow >> 2, pj = lrow & 3;
#pragma unroll
    for (int tap = 0; tap < 9; ++tap) {
      const int ti = tap / 3, tj = tap - ti * 3;
      int si = pi + ti - 1, sj = pj + tj - 1;
      bool valid = ((unsigned)si < 4u) && ((unsigned)sj < 4u);
      rel[tap] = valid ? ((si * 4 + sj) << 7) : (1 << 24);
    }
  }
  if (t < 64) {
    float sh; float sc = bn_scale(acc2, g2, b2, 64, t, sh);
    scsh[t * 2] = sc; scsh[t * 2 + 1] = sh;
  }
  const int so = t >> 1, shalf = t & 1, so7 = so & 7;
  {
    const u16* wsrc = wp + ohalf * 8192 + so * 64 + shalf * 32;
    uint4 w0 = *reinterpret_cast<const uint4*>(wsrc);
    uint4 w1 = *reinterpret_cast<const uint4*>(wsrc + 8);
    uint4 w2 = *reinterpret_cast<const uint4*>(wsrc + 16);
    uint4 w3v = *reinterpret_cast<const uint4*>(wsrc + 24);
    char* dst = (char*)ldsW[0] + so * 128;
    const int gb = shalf * 4;
    *reinterpret_cast<uint4*>(dst + (((gb + 0) ^ so7) << 4)) = w0;
    *reinterpret_cast<uint4*>(dst + (((gb + 1) ^ so7) << 4)) = w1;
    *reinterpret_cast<uint4*>(dst + (((gb + 2) ^ so7) << 4)) = w2;
    *reinterpret_cast<uint4*>(dst + (((gb + 3) ^ so7) << 4)) = w3v;
  }
  __syncthreads();
  {
    const u16* srow = src + (size_t)(Nbase + t) * 64;
    char* drow = (char*)featB + t * 128;
    const int r7 = t & 7;
#pragma unroll
    for (int g = 0; g < 8; ++g) {
      short8b v = *reinterpret_cast<const short8b*>(srow + g * 8);
      float f[8];
#pragma unroll
      for (int j = 0; j < 8; ++j) {
        const int c = g * 8 + j;
        f[j] = fmaxf(fmaf(bf2f((u16)v[j]), scsh[c * 2], scsh[c * 2 + 1]), 0.f);
      }
      uint4 pk{cvtpk(f[0], f[1]), cvtpk(f[2], f[3]), cvtpk(f[4], f[5]), cvtpk(f[6], f[7])};
      *reinterpret_cast<uint4*>(drow + ((g ^ r7) << 4)) = pk;
    }
  }
  if (t < 8) *reinterpret_cast<uint4*>((char*)featB + 32768 + t * 16) = uint4{0, 0, 0, 0};
  uint4 r0, r1, r2, r3v;
  {
    const u16* wsrc = wp + 16384 + ohalf * 8192 + so * 64 + shalf * 32;
    r0 = *reinterpret_cast<const uint4*>(wsrc);
    r1 = *reinterpret_cast<const uint4*>(wsrc + 8);
    r2 = *reinterpret_cast<const uint4*>(wsrc + 16);
    r3v = *reinterpret_cast<const uint4*>(wsrc + 24);
  }
  __syncthreads();
  f32x4 acc[4][8] = {};
  const char* fB = (const char*)featB;
  const int swzA0 = (lk << 4) ^ ((lrow & 7) << 4);
  const int swzA1 = (64 | (lk << 4)) ^ ((lrow & 7) << 4);
#pragma unroll
  for (int tap = 0; tap < 9; ++tap) {
    const int cur = tap & 1;
    const char* lW = (const char*)ldsW[cur];
    short8b aw0[4], aw1[4];
#pragma unroll
    for (int m = 0; m < 4; ++m) {
      const int rowoff = (wm * 64 + m * 16 + lrow) << 7;
      aw0[m] = *reinterpret_cast<const short8b*>(lW + rowoff + swzA0);
      aw1[m] = *reinterpret_cast<const short8b*>(lW + rowoff + swzA1);
    }
#pragma unroll
    for (int n = 0; n < 8; ++n) {
      int ad0 = ((wn * 128 + n * 16) << 7) + rel[tap];
      ad0 = ad0 < 32768 ? ad0 : 32768;
      const int swz = (ad0 >> 3) & 0x70;
      short8b bf0 = *reinterpret_cast<const short8b*>(fB + ad0 + ((lk << 4) ^ swz));
      short8b bf1 = *reinterpret_cast<const short8b*>(fB + ad0 + ((64 | (lk << 4)) ^ swz));
#pragma unroll
      for (int m = 0; m < 4; ++m) {
        acc[m][n] = __builtin_amdgcn_mfma_f32_16x16x32_bf16(aw0[m], bf0, acc[m][n], 0, 0, 0);
        acc[m][n] = __builtin_amdgcn_mfma_f32_16x16x32_bf16(aw1[m], bf1, acc[m][n], 0, 0, 0);
      }
    }
    if (tap < 8) {
      char* dst = (char*)ldsW[cur ^ 1] + so * 128;
      const int gb = shalf * 4;
      *reinterpret_cast<uint4*>(dst + (((gb + 0) ^ so7) << 4)) = r0;
      *reinterpret_cast<uint4*>(dst + (((gb + 1) ^ so7) << 4)) = r1;
      *reinterpret_cast<uint4*>(dst + (((gb + 2) ^ so7) << 4)) = r2;
      *reinterpret_cast<uint4*>(dst + (((gb + 3) ^ so7) << 4)) = r3v;
      if (tap < 7) {
        const u16* wsrc = wp + (tap + 2) * 16384 + ohalf * 8192 + so * 64 + shalf * 32;
        r0 = *reinterpret_cast<const uint4*>(wsrc);
        r1 = *reinterpret_cast<const uint4*>(wsrc + 8);
        r2 = *reinterpret_cast<const uint4*>(wsrc + 16);
        r3v = *reinterpret_cast<const uint4*>(wsrc + 24);
      }
    }
    __syncthreads();
  }
#pragma unroll
  for (int m = 0; m < 4; ++m) {
    const int o = ohalf * 128 + wm * 64 + m * 16 + lk * 4;
#pragma unroll
    for (int n = 0; n < 8; ++n) {
      const int colg = Nbase + wn * 128 + n * 16 + lrow;
      const int b = colg >> 4, p = colg & 15;
      u16* dst = y3b + (size_t)b * 4096 + (size_t)o * 16 + p;
#pragma unroll
      for (int r = 0; r < 4; ++r) dst[r * 16] = f2bf(acc[m][n][r]);
    }
  }
  float* pst = reinterpret_cast<float*>(featB);
  pst[t] = 0.f;
  __syncthreads();
#pragma unroll
  for (int m = 0; m < 4; ++m) {
#pragma unroll
    for (int r = 0; r < 4; ++r) {
      float s = 0.f, s2 = 0.f;
#pragma unroll
      for (int n = 0; n < 8; ++n) {
        float v = acc[m][n][r];
        s += v; s2 = fmaf(v, v, s2);
      }
      s += __shfl_xor(s, 1); s2 += __shfl_xor(s2, 1);
      s += __shfl_xor(s, 2); s2 += __shfl_xor(s2, 2);
      s += __shfl_xor(s, 4); s2 += __shfl_xor(s2, 4);
      s += __shfl_xor(s, 8); s2 += __shfl_xor(s2, 8);
      if (lrow == 0) {
        const int ch = wm * 64 + m * 16 + lk * 4 + r;
        atomicAdd(&pst[ch], s);
        atomicAdd(&pst[128 + ch], s2);
      }
    }
  }
  __syncthreads();
  partials3[((size_t)(ohalf * 512 + blockIdx.x)) * 256 + t] = pst[t];
}

// ---------- reduce conv3 partials -> acc3 ([S 256][S2 256]) ----------
__global__ __launch_bounds__(256) void reduce3_kernel(const float* __restrict__ p,
                                                      float* __restrict__ acc3) {
  const int c2 = blockIdx.x, t = threadIdx.x;
  const int kind = c2 >> 8, c = c2 & 255;
  const int h = c >> 7, chl = c & 127;
  float s = 0.f;
  for (int i = t; i < 512; i += 256)
    s += p[((size_t)(h * 512 + i)) * 256 + kind * 128 + chl];
#pragma unroll
  for (int off = 32; off > 0; off >>= 1) s += __shfl_down(s, off);
  __shared__ float red[4];
  if ((t & 63) == 0) red[t >> 6] = s;
  __syncthreads();
  if (t == 0) acc3[kind * 256 + c] = red[0] + red[1] + red[2] + red[3];
}

// ---------- BN3 + relu: y3b (bf16) -> d_out (fp32) ----------
__global__ __launch_bounds__(256) void final_kernel(const u16* __restrict__ y3b,
                                                    float* __restrict__ out,
                                                    const float* __restrict__ acc3,
                                                    const float* __restrict__ g3,
                                                    const float* __restrict__ b3) {
  const size_t i = ((size_t)blockIdx.x * 256 + threadIdx.x) * 8;
  const int c = (int)((i >> 4) & 255);
  float sh; const float sc = bn_scale(acc3, g3, b3, 256, c, sh);
  short8b v = *reinterpret_cast<const short8b*>(y3b + i);
  float4 o0, o1;
  o0.x = fmaxf(fmaf(bf2f((u16)v[0]), sc, sh), 0.f);
  o0.y = fmaxf(fmaf(bf2f((u16)v[1]), sc, sh), 0.f);
  o0.z = fmaxf(fmaf(bf2f((u16)v[2]), sc, sh), 0.f);
  o0.w = fmaxf(fmaf(bf2f((u16)v[3]), sc, sh), 0.f);
  o1.x = fmaxf(fmaf(bf2f((u16)v[4]), sc, sh), 0.f);
  o1.y = fmaxf(fmaf(bf2f((u16)v[5]), sc, sh), 0.f);
  o1.z = fmaxf(fmaf(bf2f((u16)v[6]), sc, sh), 0.f);
  o1.w = fmaxf(fmaf(bf2f((u16)v[7]), sc, sh), 0.f);
  *reinterpret_cast<float4*>(out + i) = o0;
  *reinterpret_cast<float4*>(out + i + 4) = o1;
}

extern "C" void kernel_launch(void* const* d_in, const int* in_sizes, int n_in,
                              void* d_out, int out_size, void* d_ws, size_t ws_size,
                              hipStream_t stream) {
  const float* x   = (const float*)d_in[0];
  const float* w1  = (const float*)d_in[1];
  const float* g1  = (const float*)d_in[3];
  const float* bb1 = (const float*)d_in[4];
  const float* wq  = (const float*)d_in[5];
  const float* wk  = (const float*)d_in[6];
  const float* wv  = (const float*)d_in[7];
  const float* rw  = (const float*)d_in[8];
  const float* rh  = (const float*)d_in[9];
  const float* g2  = (const float*)d_in[10];
  const float* bb2 = (const float*)d_in[11];
  const float* w3  = (const float*)d_in[12];
  const float* g3  = (const float*)d_in[14];
  const float* bb3 = (const float*)d_in[15];
  float* out = (float*)d_out;
  float* ws  = (float*)d_ws;

  u16*   bufb   = (u16*)ws;                 // 8,388,608 u16
  u16*   y3     = bufb + 8388608;           // 33,554,432 u16
  u16*   wp1    = y3 + 33554432;            // 46,080
  u16*   wp3    = wp1 + 46080;              // 147,456
  u16*   wqkvT  = wp3 + 147456;             // 16,384
  // u16 total = 42,152,960 -> 21,076,480 floats
  float* acc1   = ws + 21076480;            // 128
  float* acc2   = acc1 + 128;               // 128
  float* acc3   = acc2 + 128;               // 512
  float* part1  = acc3 + 512;               // 65,536
  float* part2  = part1 + 65536;            // 262,144
  float* part3  = part2 + 262144;           // 262,144

  prep_kernel<<<820, 256, 0, stream>>>(w1, w3, wq, wk, wv, rw, rh, wp1, wp3, wqkvT);
  conv1_kernel<<<512, 256, 0, stream>>>(x, wp1, bufb, part1);
  reduce12_kernel<<<128, 256, 0, stream>>>(part1, acc1, 512);
  attn_kernel<<<2048, 256, 0, stream>>>(bufb, wqkvT, acc1, g1, bb1, part2);
  reduce12_kernel<<<128, 256, 0, stream>>>(part2, acc2, 2048);
  conv3_kernel<<<dim3(512, 2), 256, 0, stream>>>(bufb, wp3, acc2, g2, bb2, y3, part3);
  reduce3_kernel<<<512, 256, 0, stream>>>(part3, acc3);
  final_kernel<<<16384, 256, 0, stream>>>(y3, out, acc3, g3, bb3);
}

// Round 8
// 156.318 us; speedup vs baseline: 2.8438x; 1.0232x over previous
//
#include <hip/hip_runtime.h>
#include <stdint.h>

// BotBlock pipeline, MFMA version (round 8).
// Block space: 8192 independent 4x4x64 blocks (raw-reshape semantics).
// buf (ws) bf16 NHWC block space: buf[row*64 + c], row = b*16 + p.
// Convs = im2col GEMMs, K = 576 (9 taps x 64 ch), bf16 MFMA 16x16x32, fp32 acc.
// attn: fully-MFMA core. qkv GEMM swapped (A=W, B=feat -> D[oc][pos]) so the
// D-fragments ARE the 16x16x16 QK^T operand fragments (q,k never touch LDS);
// S bounced 16x18 per-wave -> softmax with 2 shfl_xor reduces; PV via MFMA
// with a small V transpose bounce. q-scale 0.25 + rel tables folded in prep.

#define EPSV 1e-5f
#define INV_N (1.0f / 131072.0f)

typedef unsigned short u16;
typedef __attribute__((ext_vector_type(8))) short short8b;  // 8 bf16
typedef __attribute__((ext_vector_type(4))) short short4b;  // 4 bf16
typedef __attribute__((ext_vector_type(4))) float f32x4;

__device__ __forceinline__ u16 f2bf(float f) {
  unsigned u = __float_as_uint(f);
  u += 0x7fffu + ((u >> 16) & 1u);
  return (u16)(u >> 16);
}
__device__ __forceinline__ float bf2f(u16 h) {
  return __uint_as_float((unsigned)h << 16);
}
__device__ __forceinline__ unsigned cvtpk(float lo, float hi) {
  unsigned r;
  asm("v_cvt_pk_bf16_f32 %0, %1, %2" : "=v"(r) : "v"(lo), "v"(hi));
  return r;
}
__device__ __forceinline__ short4b pack4(unsigned lo, unsigned hi) {
  union { unsigned u[2]; short4b s; } x;
  x.u[0] = lo; x.u[1] = hi;
  return x.s;
}
__device__ __forceinline__ f32x4 mfma16(short4b a, short4b b, f32x4 c) {
#if __has_builtin(__builtin_amdgcn_mfma_f32_16x16x16_bf16)
  return __builtin_amdgcn_mfma_f32_16x16x16_bf16(a, b, c, 0, 0, 0);
#elif __has_builtin(__builtin_amdgcn_mfma_f32_16x16x16bf16_1k)
  return __builtin_amdgcn_mfma_f32_16x16x16bf16_1k(a, b, c, 0, 0, 0);
#else
  f32x4 d;
  asm volatile("v_mfma_f32_16x16x16_bf16 %0, %1, %2, %3\n\ts_nop 7\n\ts_nop 7"
               : "=v"(d) : "v"(a), "v"(b), "v"(c));
  return d;
#endif
}

__device__ __forceinline__ float bn_scale(const float* __restrict__ acc,
                                          const float* __restrict__ gam,
                                          const float* __restrict__ bet,
                                          int C, int c, float& shift) {
  float S = acc[c], S2 = acc[C + c];
  float mean = S * INV_N;
  float var  = S2 * INV_N - mean * mean;
  float rstd = rsqrtf(var + EPSV);
  float sc = gam[c] * rstd;
  shift = bet[c] - mean * sc;
  return sc;
}

// ---------- prep: conv1 w -> [18][64][40]; conv3 w -> [9][256][64]; qkv+rel -> [256][64] ----------
// q weights and rel-fold weights pre-scaled by 0.25 (= d^-0.5, d=16).
__global__ __launch_bounds__(256) void prep_kernel(const float* __restrict__ w1,
                                                   const float* __restrict__ w3,
                                                   const float* __restrict__ wq,
                                                   const float* __restrict__ wk,
                                                   const float* __restrict__ wv,
                                                   const float* __restrict__ relw,
                                                   const float* __restrict__ relh,
                                                   u16* __restrict__ wp1,
                                                   u16* __restrict__ wp3,
                                                   u16* __restrict__ wqkvT) {
  int i = blockIdx.x * 256 + threadIdx.x;
  const int tot1 = 18 * 64 * 40;       // 46080
  const int tot3 = 9 * 256 * 64;       // 147456
  if (i < tot1) {
    int ch = i / (64 * 40); int r = i - ch * 64 * 40; int o = r / 40; int kk = r - o * 40;
    float v = 0.f;
    if (kk < 32) { int k = ch * 32 + kk; int tap = k >> 6; int c = k & 63;
                   v = w1[o * 576 + c * 9 + tap]; }
    wp1[i] = f2bf(v);
  } else if (i < tot1 + tot3) {
    int j = i - tot1;
    int tap = j >> 14; int r = j & 16383; int o = r >> 6; int c = r & 63;
    wp3[j] = f2bf(w3[o * 576 + c * 9 + tap]);
  } else if (i < tot1 + tot3 + 192 * 64) {
    int j = i - tot1 - tot3;
    int oc = j >> 6, c = j & 63;
    const float* src = (oc < 64) ? wq : (oc < 128) ? wk : wv;
    float v = src[(c << 6) + (oc & 63)];
    if (oc < 64) v *= 0.25f;                       // fold q scale
    wqkvT[j] = f2bf(v);
  } else if (i < tot1 + tot3 + 192 * 64 + 4096) {
    int j = i - tot1 - tot3 - 192 * 64;  // 0..4095
    int c = j & 63; int col = (j >> 6) & 31; int tbl = j >> 11;
    int n = col >> 3, m = col & 7;
    float v = 0.f;
    if (m < 7) {
      const float* rel = tbl ? relh : relw;
#pragma unroll
      for (int d = 0; d < 16; ++d) v += wq[c * 64 + n * 16 + d] * rel[m * 16 + d];
      v *= 0.25f;                                  // fold q scale
    }
    wqkvT[(192 + tbl * 32 + col) * 64 + c] = f2bf(v);
  }
}

// ---------- conv1: x (NCHW blocks, fp32) -> buf (NHWC bf16) + fused stats1 ----------
__global__ __launch_bounds__(256) void conv1_kernel(const float* __restrict__ x,
                                                    const u16* __restrict__ wp,
                                                    u16* __restrict__ bufb,
                                                    float* __restrict__ partials1) {
  __shared__ __align__(16) char featA[257 * 128];   // bf16 [row][64ch], swizzled; row 256 = zeros
  __shared__ __align__(16) char ldsW[2][64 * 80];   // [o][40 bf16] per 32-k chunk
  const int t = threadIdx.x;
  const int lane = t & 63, w = t >> 6;
  const int lrow = lane & 15, lk = lane >> 4;
  const int wm = w >> 1, wn = w & 1;                // wave tile: 128 rows x 32 o
  const size_t Mbase = (size_t)blockIdx.x * 256;

  int rel[9];
  {
    const int pi = lrow >> 2, pj = lrow & 3;
#pragma unroll
    for (int tap = 0; tap < 9; ++tap) {
      const int ti = tap / 3, tj = tap - ti * 3;
      int si = pi + ti - 1, sj = pj + tj - 1;
      bool valid = ((unsigned)si < 4u) && ((unsigned)sj < 4u);
      rel[tap] = valid ? ((si * 4 + sj) << 7) : (1 << 24);
    }
  }

  {
    const int cp = t >> 3, ph = t & 7;
    const int gsw = ((cp >> 2) << 4) | ((cp & 3) << 2);
#pragma unroll
    for (int i = 0; i < 16; ++i) {
      const float* bp = x + Mbase * 64 + i * 1024 + cp * 32 + ph * 2;
      float2 a = *reinterpret_cast<const float2*>(bp);
      float2 b = *reinterpret_cast<const float2*>(bp + 16);
#pragma unroll
      for (int j = 0; j < 2; ++j) {
        const int row = i * 16 + ph * 2 + j;
        unsigned pk = cvtpk(j ? a.y : a.x, j ? b.y : b.x);
        const int byte = row * 128 + (gsw ^ ((row & 7) << 4));
        *reinterpret_cast<unsigned*>(featA + byte) = pk;
      }
    }
  }
  if (t < 8) *reinterpret_cast<uint4*>(featA + 256 * 128 + t * 16) = uint4{0, 0, 0, 0};

  uint4 s0, s1;
  {
    const u16* sp = wp;
    s0 = *reinterpret_cast<const uint4*>(sp + (size_t)t * 8);
    if (t < 64) s1 = *reinterpret_cast<const uint4*>(sp + (size_t)(t + 256) * 8);
    *reinterpret_cast<uint4*>(ldsW[0] + t * 16) = s0;
    if (t < 64) *reinterpret_cast<uint4*>(ldsW[0] + (t + 256) * 16) = s1;
  }
  __syncthreads();

  f32x4 acc[8][2] = {};
#pragma unroll
  for (int chn = 0; chn < 18; ++chn) {
    const int cur = chn & 1;
    const int tap = chn >> 1, kk = chn & 1;
    if (chn + 1 < 18) {
      const u16* sp = wp + (chn + 1) * 2560;
      s0 = *reinterpret_cast<const uint4*>(sp + (size_t)t * 8);
      if (t < 64) s1 = *reinterpret_cast<const uint4*>(sp + (size_t)(t + 256) * 8);
    }
    const int kkg = (kk << 6) | (lk << 4);
    short8b bw[2];
#pragma unroll
    for (int n = 0; n < 2; ++n)
      bw[n] = *reinterpret_cast<const short8b*>(ldsW[cur] + (wn * 32 + n * 16 + lrow) * 80 + lk * 16);
#pragma unroll
    for (int m = 0; m < 8; ++m) {
      int ad = ((wm * 128 + m * 16) << 7) + rel[tap];
      ad = ad < 32768 ? ad : 32768;
      ad += (kkg ^ ((ad >> 3) & 0x70));
      short8b af = *reinterpret_cast<const short8b*>(featA + ad);
#pragma unroll
      for (int n = 0; n < 2; ++n)
        acc[m][n] = __builtin_amdgcn_mfma_f32_16x16x32_bf16(af, bw[n], acc[m][n], 0, 0, 0);
    }
    if (chn + 1 < 18) {
      *reinterpret_cast<uint4*>(ldsW[cur ^ 1] + t * 16) = s0;
      if (t < 64) *reinterpret_cast<uint4*>(ldsW[cur ^ 1] + (t + 256) * 16) = s1;
    }
    __syncthreads();
  }

#pragma unroll
  for (int m = 0; m < 8; ++m) {
    const size_t rowg0 = Mbase + wm * 128 + m * 16 + lk * 4;
#pragma unroll
    for (int n = 0; n < 2; ++n) {
      const int o = wn * 32 + n * 16 + lrow;
#pragma unroll
      for (int r = 0; r < 4; ++r)
        bufb[(rowg0 + r) * 64 + o] = f2bf(acc[m][n][r]);
    }
  }

  float* pst = reinterpret_cast<float*>(featA);    // [S 64][S2 64]
  if (t < 128) pst[t] = 0.f;
  __syncthreads();
#pragma unroll
  for (int n = 0; n < 2; ++n) {
    float s = 0.f, s2 = 0.f;
#pragma unroll
    for (int m = 0; m < 8; ++m)
#pragma unroll
      for (int r = 0; r < 4; ++r) {
        float v = acc[m][n][r];
        s += v; s2 = fmaf(v, v, s2);
      }
    s += __shfl_xor(s, 16); s2 += __shfl_xor(s2, 16);
    s += __shfl_xor(s, 32); s2 += __shfl_xor(s2, 32);
    if (lk == 0) {
      const int o = wn * 32 + n * 16 + lrow;
      atomicAdd(&pst[o], s);
      atomicAdd(&pst[64 + o], s2);
    }
  }
  __syncthreads();
  if (t < 128) partials1[(size_t)blockIdx.x * 128 + t] = pst[t];
}

// ---------- generic partial reduce for stats1/stats2 (stride 128) ----------
__global__ __launch_bounds__(256) void reduce12_kernel(const float* __restrict__ p,
                                                       float* __restrict__ acc, int nrows) {
  const int c = blockIdx.x, t = threadIdx.x;
  float s = 0.f;
  for (int i = t; i < nrows; i += 256) s += p[(size_t)i * 128 + c];
#pragma unroll
  for (int off = 32; off > 0; off >>= 1) s += __shfl_down(s, off);
  __shared__ float red[4];
  if ((t & 63) == 0) red[t >> 6] = s;
  __syncthreads();
  if (t == 0) acc[c] = red[0] + red[1] + red[2] + red[3];
}

// ---------- attn: BN1+relu -> qkv+rel (MFMA, swapped) -> MFMA attention core ----------
// 256 thr = 4 independent waves, one block each. All core LDS is wave-private
// (no barriers after the initial scsh sync).
__global__ __launch_bounds__(256) void attn_kernel(u16* __restrict__ buf,
                                                   const u16* __restrict__ wqkvT,
                                                   const float* __restrict__ acc1,
                                                   const float* __restrict__ g1,
                                                   const float* __restrict__ b1,
                                                   float* __restrict__ partials2) {
  __shared__ float scsh[64][2];
  __shared__ float pstA[128];
  __shared__ __align__(16) u16 feat_l[4][1024];     // bf16 [pos][64c], granule-swizzled
  __shared__ __align__(16) float S_lds[4][16 * 18]; // per-wave S bounce [q][kp] pad18
  __shared__ __align__(16) u16 V_lds[4][16 * 20];   // per-wave V bounce [kp][d] pad20
  __shared__ __align__(16) float inv_lds[4][16];
  __shared__ __align__(16) u16 rLs[4][1152];        // bf16 rel tables [tbl2][n4][pos16][9]
  const int t = threadIdx.x, u = t >> 6, lane = t & 63;
  const size_t b = (size_t)blockIdx.x * 4 + u;
  const int lrow = lane & 15, lk = lane >> 4;
  float* Sl = S_lds[u];
  u16* Vl = V_lds[u];
  float* invl = inv_lds[u];
  u16* rL = rLs[u];

  if (t < 64) {
    float sh; float sc = bn_scale(acc1, g1, b1, 64, t, sh);
    scsh[t][0] = sc; scsh[t][1] = sh;
  }
  if (t < 128) pstA[t] = 0.f;
  __syncthreads();

  // ---- stage feat (BN1+relu on bf16 buf) ----
  {
    const int pos = lane >> 2, cq = lane & 3;
    const u16* src = buf + b * 1024 + pos * 64 + cq * 16;
    short8b v0 = *reinterpret_cast<const short8b*>(src);
    short8b v1 = *reinterpret_cast<const short8b*>(src + 8);
    float f[16];
#pragma unroll
    for (int j = 0; j < 8; ++j) {
      const int c0 = cq * 16 + j, c1 = cq * 16 + 8 + j;
      f[j]     = fmaxf(fmaf(bf2f((u16)v0[j]), scsh[c0][0], scsh[c0][1]), 0.f);
      f[8 + j] = fmaxf(fmaf(bf2f((u16)v1[j]), scsh[c1][0], scsh[c1][1]), 0.f);
    }
    uint4 q0{cvtpk(f[0], f[1]), cvtpk(f[2], f[3]), cvtpk(f[4], f[5]), cvtpk(f[6], f[7])};
    uint4 q1{cvtpk(f[8], f[9]), cvtpk(f[10], f[11]), cvtpk(f[12], f[13]), cvtpk(f[14], f[15])};
    const int g0 = (cq * 2) ^ (pos & 7), g1g = (cq * 2 + 1) ^ (pos & 7);
    *reinterpret_cast<uint4*>(&feat_l[u][pos * 64 + g0 * 8]) = q0;
    *reinterpret_cast<uint4*>(&feat_l[u][pos * 64 + g1g * 8]) = q1;
  }

  // ---- qkv + rel GEMM, SWAPPED: A = weights (M=oc), B = feat (N=pos) ----
  // D per tile: lane holds pos = lrow, oc = ct*16 + lk*4 + r  -> D-frags ARE
  // the 16x16x16 QK operand frags (q: A[row=pos][d], k: B[col=pos][d]).
  short8b bfeat[2];
#pragma unroll
  for (int ch = 0; ch < 2; ++ch) {
    const int kg = ch * 4 + lk;
    bfeat[ch] = *reinterpret_cast<const short8b*>(&feat_l[u][lrow * 64 + ((kg ^ (lrow & 7)) * 8)]);
  }
  short4b qf[4], kf[4];
  uint2 vf[4];
#pragma unroll
  for (int ct = 0; ct < 16; ++ct) {
    f32x4 d = {0.f, 0.f, 0.f, 0.f};
#pragma unroll
    for (int ch = 0; ch < 2; ++ch) {
      short8b wfr = *reinterpret_cast<const short8b*>(&wqkvT[(ct * 16 + lrow) * 64 + ch * 32 + lk * 8]);
      d = __builtin_amdgcn_mfma_f32_16x16x32_bf16(wfr, bfeat[ch], d, 0, 0, 0);
    }
    if (ct < 4) {
      qf[ct] = pack4(cvtpk(d[0], d[1]), cvtpk(d[2], d[3]));
    } else if (ct < 8) {
      kf[ct - 4] = pack4(cvtpk(d[0], d[1]), cvtpk(d[2], d[3]));
    } else if (ct < 12) {
      vf[ct - 8] = uint2{cvtpk(d[0], d[1]), cvtpk(d[2], d[3])};
    } else {
#pragma unroll
      for (int r = 0; r < 4; ++r) {
        const int rc = (ct - 12) * 16 + lk * 4 + r;
        const int tbl = rc >> 5, col = rc & 31;
        rL[tbl * 576 + (col >> 3) * 144 + lrow * 9 + (col & 7)] = f2bf(d[r]);
      }
    }
  }

  // ---- per-head MFMA attention core (wave-private, no barriers) ----
  const f32x4 fzero = {0.f, 0.f, 0.f, 0.f};
  const int qj3 = 3 - (lrow & 3);
  const int qi = lrow >> 2;
#pragma unroll
  for (int n = 0; n < 4; ++n) {
    // S[q][kp] = q . k^T   (lane: q = lk*4+r, kp = lrow)
    f32x4 S = mfma16(qf[n], kf[n], fzero);
#pragma unroll
    for (int r = 0; r < 4; ++r) Sl[(lk * 4 + r) * 18 + lrow] = S[r];
    // reload transposed: lane owns row q = lrow, kp = lk*4..+4
    const float* srow = Sl + lrow * 18 + lk * 4;
    float2 sa = *reinterpret_cast<const float2*>(srow);
    float2 sb = *reinterpret_cast<const float2*>(srow + 2);
    float s0 = sa.x, s1 = sa.y, s2 = sb.x, s3 = sb.y;
    // rel logits (bf16 tables; kpj = j, kpi = lk for kp = lk*4+j)
    const u16* rwp = rL + n * 144 + lrow * 9 + qj3;
    const float rh = bf2f(rL[576 + n * 144 + lrow * 9 + 3 + lk - qi]);
    s0 += bf2f(rwp[0]) + rh; s1 += bf2f(rwp[1]) + rh;
    s2 += bf2f(rwp[2]) + rh; s3 += bf2f(rwp[3]) + rh;
    // softmax over kp: local 4 + xor16 + xor32
    float m = fmaxf(fmaxf(s0, s1), fmaxf(s2, s3));
    m = fmaxf(m, __shfl_xor(m, 16)); m = fmaxf(m, __shfl_xor(m, 32));
    float p0 = __expf(s0 - m), p1 = __expf(s1 - m);
    float p2 = __expf(s2 - m), p3 = __expf(s3 - m);
    float ls = p0 + p1 + p2 + p3;
    ls += __shfl_xor(ls, 16); ls += __shfl_xor(ls, 32);
    if (lk == 0) invl[lrow] = 1.f / ls;
    short4b pf = pack4(cvtpk(p0, p1), cvtpk(p2, p3));
    // V transpose bounce: write [vpos=lrow][d=lk*4..+4], read [kp=lk*4+j][d=lrow]
    *reinterpret_cast<uint2*>(Vl + lrow * 20 + lk * 4) = vf[n];
    const int vb = lk * 4;
    unsigned v0 = Vl[(vb + 0) * 20 + lrow], v1 = Vl[(vb + 1) * 20 + lrow];
    unsigned v2 = Vl[(vb + 2) * 20 + lrow], v3 = Vl[(vb + 3) * 20 + lrow];
    short4b vB = pack4(v0 | (v1 << 16), v2 | (v3 << 16));
    // O[q][d] = P . V   (lane: q = lk*4+r, d = lrow)
    f32x4 O = mfma16(pf, vB, fzero);
    float4 iv = *reinterpret_cast<const float4*>(invl + lk * 4);
    float o0 = O[0] * iv.x, o1 = O[1] * iv.y, o2 = O[2] * iv.z, o3 = O[3] * iv.w;
    // bf16 output (NHWC in-place)
    u16* ob = buf + b * 1024 + (n << 4) + lrow;
    ob[(lk * 4 + 0) * 64] = f2bf(o0); ob[(lk * 4 + 1) * 64] = f2bf(o1);
    ob[(lk * 4 + 2) * 64] = f2bf(o2); ob[(lk * 4 + 3) * 64] = f2bf(o3);
    // fused stats2 (channel c = n*16 + d)
    float ss = o0 + o1 + o2 + o3;
    float s2s = o0 * o0 + o1 * o1 + o2 * o2 + o3 * o3;
    ss += __shfl_xor(ss, 16); s2s += __shfl_xor(s2s, 16);
    ss += __shfl_xor(ss, 32); s2s += __shfl_xor(s2s, 32);
    if (lk == 0) {
      atomicAdd(&pstA[(n << 4) + lrow], ss);
      atomicAdd(&pstA[64 + (n << 4) + lrow], s2s);
    }
  }
  __syncthreads();
  if (t < 128) partials2[(size_t)blockIdx.x * 128 + t] = pstA[t];
}

// ---------- conv3: BN2+relu(buf bf16 NHWC) -> y3b (bf16 NCHW) + fused stats3 ----------
__global__ __launch_bounds__(256, 2) void conv3_kernel(const u16* __restrict__ src,
                                                       const u16* __restrict__ wp,
                                                       const float* __restrict__ acc2,
                                                       const float* __restrict__ g2,
                                                       const float* __restrict__ b2,
                                                       u16* __restrict__ y3b,
                                                       float* __restrict__ partials3) {
  __shared__ __align__(16) u16 featB[257 * 64];
  __shared__ __align__(16) u16 ldsW[2][128 * 64];
  __shared__ float scsh[128];
  const int t = threadIdx.x;
  const int lane = t & 63, w = t >> 6;
  const int lrow = lane & 15, lk = lane >> 4;
  const int wm = w >> 1, wn = w & 1;
  const int Nbase = blockIdx.x * 256;
  const int ohalf = blockIdx.y;

  int rel[9];
  {
    const int pi = lrow >> 2, pj = lrow & 3;
#pragma unroll
    for (int tap = 0; tap < 9; ++tap) {
      const int ti = tap / 3, tj = tap - ti * 3;
      int si = pi + ti - 1, sj = pj + tj - 1;
      bool valid = ((unsigned)si < 4u) && ((unsigned)sj < 4u);
      rel[tap] = valid ? ((si * 4 + sj) << 7) : (1 << 24);
    }
  }
  if (t < 64) {
    float sh; float sc = bn_scale(acc2, g2, b2, 64, t, sh);
    scsh[t * 2] = sc; scsh[t * 2 + 1] = sh;
  }
  const int so = t >> 1, shalf = t & 1, so7 = so & 7;
  {
    const u16* wsrc = wp + ohalf * 8192 + so * 64 + shalf * 32;
    uint4 w0 = *reinterpret_cast<const uint4*>(wsrc);
    uint4 w1 = *reinterpret_cast<const uint4*>(wsrc + 8);
    uint4 w2 = *reinterpret_cast<const uint4*>(wsrc + 16);
    uint4 w3v = *reinterpret_cast<const uint4*>(wsrc + 24);
    char* dst = (char*)ldsW[0] + so * 128;
    const int gb = shalf * 4;
    *reinterpret_cast<uint4*>(dst + (((gb + 0) ^ so7) << 4)) = w0;
    *reinterpret_cast<uint4*>(dst + (((gb + 1) ^ so7) << 4)) = w1;
    *reinterpret_cast<uint4*>(dst + (((gb + 2) ^ so7) << 4)) = w2;
    *reinterpret_cast<uint4*>(dst + (((gb + 3) ^ so7) << 4)) = w3v;
  }
  __syncthreads();
  {
    const u16* srow = src + (size_t)(Nbase + t) * 64;
    char* drow = (char*)featB + t * 128;
    const int r7 = t & 7;
#pragma unroll
    for (int g = 0; g < 8; ++g) {
      short8b v = *reinterpret_cast<const short8b*>(srow + g * 8);
      float f[8];
#pragma unroll
      for (int j = 0; j < 8; ++j) {
        const int c = g * 8 + j;
        f[j] = fmaxf(fmaf(bf2f((u16)v[j]), scsh[c * 2], scsh[c * 2 + 1]), 0.f);
      }
      uint4 pk{cvtpk(f[0], f[1]), cvtpk(f[2], f[3]), cvtpk(f[4], f[5]), cvtpk(f[6], f[7])};
      *reinterpret_cast<uint4*>(drow + ((g ^ r7) << 4)) = pk;
    }
  }
  if (t < 8) *reinterpret_cast<uint4*>((char*)featB + 32768 + t * 16) = uint4{0, 0, 0, 0};
  uint4 r0, r1, r2, r3v;
  {
    const u16* wsrc = wp + 16384 + ohalf * 8192 + so * 64 + shalf * 32;
    r0 = *reinterpret_cast<const uint4*>(wsrc);
    r1 = *reinterpret_cast<const uint4*>(wsrc + 8);
    r2 = *reinterpret_cast<const uint4*>(wsrc + 16);
    r3v = *reinterpret_cast<const uint4*>(wsrc + 24);
  }
  __syncthreads();
  f32x4 acc[4][8] = {};
  const char* fB = (const char*)featB;
  const int swzA0 = (lk << 4) ^ ((lrow & 7) << 4);
  const int swzA1 = (64 | (lk << 4)) ^ ((lrow & 7) << 4);
#pragma unroll
  for (int tap = 0; tap < 9; ++tap) {
    const int cur = tap & 1;
    const char* lW = (const char*)ldsW[cur];
    short8b aw0[4], aw1[4];
#pragma unroll
    for (int m = 0; m < 4; ++m) {
      const int rowoff = (wm * 64 + m * 16 + lrow) << 7;
      aw0[m] = *reinterpret_cast<const short8b*>(lW + rowoff + swzA0);
      aw1[m] = *reinterpret_cast<const short8b*>(lW + rowoff + swzA1);
    }
#pragma unroll
    for (int n = 0; n < 8; ++n) {
      int ad0 = ((wn * 128 + n * 16) << 7) + rel[tap];
      ad0 = ad0 < 32768 ? ad0 : 32768;
      const int swz = (ad0 >> 3) & 0x70;
      short8b bf0 = *reinterpret_cast<const short8b*>(fB + ad0 + ((lk << 4) ^ swz));
      short8b bf1 = *reinterpret_cast<const short8b*>(fB + ad0 + ((64 | (lk << 4)) ^ swz));
#pragma unroll
      for (int m = 0; m < 4; ++m) {
        acc[m][n] = __builtin_amdgcn_mfma_f32_16x16x32_bf16(aw0[m], bf0, acc[m][n], 0, 0, 0);
        acc[m][n] = __builtin_amdgcn_mfma_f32_16x16x32_bf16(aw1[m], bf1, acc[m][n], 0, 0, 0);
      }
    }
    if (tap < 8) {
      char* dst = (char*)ldsW[cur ^ 1] + so * 128;
      const int gb = shalf * 4;
      *reinterpret_cast<uint4*>(dst + (((gb + 0) ^ so7) << 4)) = r0;
      *reinterpret_cast<uint4*>(dst + (((gb + 1) ^ so7) << 4)) = r1;
      *reinterpret_cast<uint4*>(dst + (((gb + 2) ^ so7) << 4)) = r2;
      *reinterpret_cast<uint4*>(dst + (((gb + 3) ^ so7) << 4)) = r3v;
      if (tap < 7) {
        const u16* wsrc = wp + (tap + 2) * 16384 + ohalf * 8192 + so * 64 + shalf * 32;
        r0 = *reinterpret_cast<const uint4*>(wsrc);
        r1 = *reinterpret_cast<const uint4*>(wsrc + 8);
        r2 = *reinterpret_cast<const uint4*>(wsrc + 16);
        r3v = *reinterpret_cast<const uint4*>(wsrc + 24);
      }
    }
    __syncthreads();
  }
#pragma unroll
  for (int m = 0; m < 4; ++m) {
    const int o = ohalf * 128 + wm * 64 + m * 16 + lk * 4;
#pragma unroll
    for (int n = 0; n < 8; ++n) {
      const int colg = Nbase + wn * 128 + n * 16 + lrow;
      const int b = colg >> 4, p = colg & 15;
      u16* dst = y3b + (size_t)b * 4096 + (size_t)o * 16 + p;
#pragma unroll
      for (int r = 0; r < 4; ++r) dst[r * 16] = f2bf(acc[m][n][r]);
    }
  }
  float* pst = reinterpret_cast<float*>(featB);
  pst[t] = 0.f;
  __syncthreads();
#pragma unroll
  for (int m = 0; m < 4; ++m) {
#pragma unroll
    for (int r = 0; r < 4; ++r) {
      float s = 0.f, s2 = 0.f;
#pragma unroll
      for (int n = 0; n < 8; ++n) {
        float v = acc[m][n][r];
        s += v; s2 = fmaf(v, v, s2);
      }
      s += __shfl_xor(s, 1); s2 += __shfl_xor(s2, 1);
      s += __shfl_xor(s, 2); s2 += __shfl_xor(s2, 2);
      s += __shfl_xor(s, 4); s2 += __shfl_xor(s2, 4);
      s += __shfl_xor(s, 8); s2 += __shfl_xor(s2, 8);
      if (lrow == 0) {
        const int ch = wm * 64 + m * 16 + lk * 4 + r;
        atomicAdd(&pst[ch], s);
        atomicAdd(&pst[128 + ch], s2);
      }
    }
  }
  __syncthreads();
  partials3[((size_t)(ohalf * 512 + blockIdx.x)) * 256 + t] = pst[t];
}

// ---------- reduce conv3 partials -> acc3 ([S 256][S2 256]) ----------
__global__ __launch_bounds__(256) void reduce3_kernel(const float* __restrict__ p,
                                                      float* __restrict__ acc3) {
  const int c2 = blockIdx.x, t = threadIdx.x;
  const int kind = c2 >> 8, c = c2 & 255;
  const int h = c >> 7, chl = c & 127;
  float s = 0.f;
  for (int i = t; i < 512; i += 256)
    s += p[((size_t)(h * 512 + i)) * 256 + kind * 128 + chl];
#pragma unroll
  for (int off = 32; off > 0; off >>= 1) s += __shfl_down(s, off);
  __shared__ float red[4];
  if ((t & 63) == 0) red[t >> 6] = s;
  __syncthreads();
  if (t == 0) acc3[kind * 256 + c] = red[0] + red[1] + red[2] + red[3];
}

// ---------- BN3 + relu: y3b (bf16) -> d_out (fp32) ----------
__global__ __launch_bounds__(256) void final_kernel(const u16* __restrict__ y3b,
                                                    float* __restrict__ out,
                                                    const float* __restrict__ acc3,
                                                    const float* __restrict__ g3,
                                                    const float* __restrict__ b3) {
  const size_t i = ((size_t)blockIdx.x * 256 + threadIdx.x) * 8;
  const int c = (int)((i >> 4) & 255);
  float sh; const float sc = bn_scale(acc3, g3, b3, 256, c, sh);
  short8b v = *reinterpret_cast<const short8b*>(y3b + i);
  float4 o0, o1;
  o0.x = fmaxf(fmaf(bf2f((u16)v[0]), sc, sh), 0.f);
  o0.y = fmaxf(fmaf(bf2f((u16)v[1]), sc, sh), 0.f);
  o0.z = fmaxf(fmaf(bf2f((u16)v[2]), sc, sh), 0.f);
  o0.w = fmaxf(fmaf(bf2f((u16)v[3]), sc, sh), 0.f);
  o1.x = fmaxf(fmaf(bf2f((u16)v[4]), sc, sh), 0.f);
  o1.y = fmaxf(fmaf(bf2f((u16)v[5]), sc, sh), 0.f);
  o1.z = fmaxf(fmaf(bf2f((u16)v[6]), sc, sh), 0.f);
  o1.w = fmaxf(fmaf(bf2f((u16)v[7]), sc, sh), 0.f);
  *reinterpret_cast<float4*>(out + i) = o0;
  *reinterpret_cast<float4*>(out + i + 4) = o1;
}

extern "C" void kernel_launch(void* const* d_in, const int* in_sizes, int n_in,
                              void* d_out, int out_size, void* d_ws, size_t ws_size,
                              hipStream_t stream) {
  const float* x   = (const float*)d_in[0];
  const float* w1  = (const float*)d_in[1];
  const float* g1  = (const float*)d_in[3];
  const float* bb1 = (const float*)d_in[4];
  const float* wq  = (const float*)d_in[5];
  const float* wk  = (const float*)d_in[6];
  const float* wv  = (const float*)d_in[7];
  const float* rw  = (const float*)d_in[8];
  const float* rh  = (const float*)d_in[9];
  const float* g2  = (const float*)d_in[10];
  const float* bb2 = (const float*)d_in[11];
  const float* w3  = (const float*)d_in[12];
  const float* g3  = (const float*)d_in[14];
  const float* bb3 = (const float*)d_in[15];
  float* out = (float*)d_out;
  float* ws  = (float*)d_ws;

  u16*   bufb   = (u16*)ws;                 // 8,388,608 u16
  u16*   y3     = bufb + 8388608;           // 33,554,432 u16
  u16*   wp1    = y3 + 33554432;            // 46,080
  u16*   wp3    = wp1 + 46080;              // 147,456
  u16*   wqkvT  = wp3 + 147456;             // 16,384
  // u16 total = 42,152,960 -> 21,076,480 floats
  float* acc1   = ws + 21076480;            // 128
  float* acc2   = acc1 + 128;               // 128
  float* acc3   = acc2 + 128;               // 512
  float* part1  = acc3 + 512;               // 65,536
  float* part2  = part1 + 65536;            // 262,144
  float* part3  = part2 + 262144;           // 262,144

  prep_kernel<<<820, 256, 0, stream>>>(w1, w3, wq, wk, wv, rw, rh, wp1, wp3, wqkvT);
  conv1_kernel<<<512, 256, 0, stream>>>(x, wp1, bufb, part1);
  reduce12_kernel<<<128, 256, 0, stream>>>(part1, acc1, 512);
  attn_kernel<<<2048, 256, 0, stream>>>(bufb, wqkvT, acc1, g1, bb1, part2);
  reduce12_kernel<<<128, 256, 0, stream>>>(part2, acc2, 2048);
  conv3_kernel<<<dim3(512, 2), 256, 0, stream>>>(bufb, wp3, acc2, g2, bb2, y3, part3);
  reduce3_kernel<<<512, 256, 0, stream>>>(part3, acc3);
  final_kernel<<<16384, 256, 0, stream>>>(y3, out, acc3, g3, bb3);
}